// Round 8
// baseline (257.773 us; speedup 1.0000x reference)
//
#include <hip/hip_runtime.h>
#include <hip/hip_bf16.h>

typedef __hip_bfloat16 bf16;
using short8 = __attribute__((ext_vector_type(8))) short;
using f32x4  = __attribute__((ext_vector_type(4))) float;

#define DEV static __device__ __forceinline__

DEV float b2f(bf16 x) { return __bfloat162float(x); }
DEV float ldf(const void* p, long i, int isb) {
  return isb ? b2f(((const bf16*)p)[i]) : ((const float*)p)[i];
}
DEV void stf(void* p, long i, float v, int isb) {
  if (isb) ((bf16*)p)[i] = __float2bfloat16(v);
  else     ((float*)p)[i] = v;
}
DEV unsigned short f2bu(float f) {
  union { bf16 h; unsigned short u; } v; v.h = __float2bfloat16(f); return v.u;
}
DEV float bu2f(unsigned short u) {
  union { unsigned u; float f; } v; v.u = ((unsigned)u) << 16; return v.f;
}
DEV float lo2f(unsigned u) { union { unsigned x; float f; } v; v.x = u << 16; return v.f; }
DEV float hi2f(unsigned u) { union { unsigned x; float f; } v; v.x = u & 0xFFFF0000u; return v.f; }
DEV unsigned pk2(float a, float b) { return (unsigned)f2bu(a) | ((unsigned)f2bu(b) << 16); }
DEV short ldb(const void* p, long i, int isb) {
  if (isb) return ((const short*)p)[i];
  union { bf16 h; short s; } v; v.h = __float2bfloat16(((const float*)p)[i]); return v.s;
}

// ---- problem constants ----
#define N_ATOMS 2500
#define N_EDGES 40000

constexpr int cK[4]    = {128, 96, 64, 32};
constexpr int cPL[4]   = {0, 2, 2, 4};
constexpr int cLO[4]   = {96, 64, 32, 0};
constexpr int cSOFF[4] = {0, 32, 320, 608};     // pooled-buffer section offsets (f32 LDS)
constexpr int cAOF[4]  = {0, 1, 10, 19};        // acc-register offset per l (total 44)
// ws float-offsets
constexpr int cWR1[4] = {0, 512, 896, 1152};
constexpr int cWR2[4] = {1280, 9472, 15616, 19712};
constexpr int cWL[4]  = {21760, 38144, 47360, 51456};
constexpr int cUOF[4] = {52480, 52481, 52481, 52562};
constexpr int FLAG_OFF = 53240;
// rad2: [e][352 ushorts]: sec0@0 (32x1), sec1@32 (32x2), sec2@96 (32x4,3 used), sec3@224 (32x4)
constexpr int RAD2_OFF = 53248;                        // 40000*176 floats
// S2: [e][168 ushorts]: S0@0, l1@2+2q (q<9), l2@24+4q (3 used), l3@64+4q (q<25)
constexpr int S2_OFF   = RAD2_OFF + N_EDGES * 176;     // 7,093,248
// unc2: [a][2080 ushorts]: sec0@0 (32x1), sec1@32+16k (9 used), sec2@544+16k (9 used), sec3@1056+32k (25 used)
constexpr int UNC2_OFF = S2_OFF + N_EDGES * 84;        // 10,453,248
constexpr int CCG_OFF  = UNC2_OFF + N_ATOMS * 1040;    // 13,053,248
constexpr int CSR_OFF   = CCG_OFF + N_ATOMS * 480;     // 14,253,248
constexpr int CNT_OFF   = CSR_OFF;
constexpr int START_OFF = CSR_OFF + 2500;
constexpr int FILL_OFF  = CSR_OFF + 5008;
constexpr int ELIST_OFF = CSR_OFF + 7512;

constexpr int cCB[4]  = {0, 128, 416, 736};
constexpr int cOUT[4] = {0, 320000, 1040000, 1840000};
constexpr int cUO2[4] = {0, 32, 544, 1056};    // unc2 section bases
constexpr int cPW2[4] = {1, 16, 16, 32};       // unc2 per-k row widths

// combo tables for couple/concat epilogue
__device__ const int c_tl[30]  = {0,0,0,0, 1,1,1,1,1,1,1,1,1, 2,2,2,2,2,2,2,2,2,2, 3,3,3,3,3,3,3};
__device__ const int c_tmm[30] = {0,0,0,0, 0,0,0,1,1,1,2,2,2, 0,0,1,1,2,2,3,3,4,4, 0,1,2,3,4,5,6};
__device__ const int c_ts[30]  = {0,1,2,3, 0,1,2,0,1,2,0,1,2, 0,1,0,1,0,1,0,1,0,1, 0,0,0,0,0,0,0};
__device__ const int c_soff_r[4] = {0, 32, 320, 608};
__device__ const int c_uof_r[4]  = {52480, 52481, 52481, 52562};
__device__ const int c_pl_r[4]   = {0, 2, 2, 4};

// ---------------- k_detect ----------------
__global__ void k_detect(const void* __restrict__ w2_0, int* __restrict__ flag) {
  if (threadIdx.x != 0 || blockIdx.x != 0) return;
  const unsigned* w = (const unsigned*)w2_0;
  int ok = 0;
  for (int i = 0; i < 512; ++i) {
    unsigned lo = w[i] & 0xFFFFu;
    unsigned e = (lo >> 7) & 0xFFu;
    if (lo == 0u || (e >= 100u && e <= 140u)) ok++;
  }
  *flag = (ok >= 256) ? 1 : 0;
}

// ---------------- k_prep ----------------
__global__ __launch_bounds__(256) void k_prep(
    const void* __restrict__ w10, const void* __restrict__ w11, const void* __restrict__ w12, const void* __restrict__ w13,
    const void* __restrict__ w20, const void* __restrict__ w21, const void* __restrict__ w22, const void* __restrict__ w23,
    const void* __restrict__ wl0, const void* __restrict__ wl1, const void* __restrict__ wl2, const void* __restrict__ wl3,
    const void* __restrict__ u0, const void* __restrict__ u2, const void* __restrict__ u4,
    const int* __restrict__ flag, float* __restrict__ ws) {
  int i = blockIdx.x * 256 + threadIdx.x;
  if (i >= 53187) return;
  int isb = *flag;
  const void* src; int base;
  if      (i < 512)   { src = w10; base = 0; }
  else if (i < 896)   { src = w11; base = 512; }
  else if (i < 1152)  { src = w12; base = 896; }
  else if (i < 1280)  { src = w13; base = 1152; }
  else if (i < 9472)  { src = w20; base = 1280; }
  else if (i < 15616) { src = w21; base = 9472; }
  else if (i < 19712) { src = w22; base = 15616; }
  else if (i < 21760) { src = w23; base = 19712; }
  else if (i < 38144) { src = wl0; base = 21760; }
  else if (i < 47360) { src = wl1; base = 38144; }
  else if (i < 51456) { src = wl2; base = 47360; }
  else if (i < 52480) { src = wl3; base = 51456; }
  else if (i < 52481) { src = u0;  base = 52480; }
  else if (i < 52562) { src = u2;  base = 52481; }
  else                { src = u4;  base = 52562; }
  ws[i] = ldf(src, i - base, isb);
}

// ---------------- CSR build ----------------
__global__ __launch_bounds__(256) void k_count(const int* __restrict__ centers, int* __restrict__ cnt) {
  int e = blockIdx.x * 256 + threadIdx.x;
  if (e < N_EDGES) atomicAdd(&cnt[centers[e]], 1);
}

__global__ __launch_bounds__(256) void k_scan(const int* __restrict__ cnt,
                                              int* __restrict__ start, int* __restrict__ fill) {
  __shared__ int part[256];
  int t = threadIdx.x;
  int loc[10];
  int s = 0;
  int base = t * 10;
#pragma unroll
  for (int i = 0; i < 10; ++i) {
    int c = (base + i < N_ATOMS) ? cnt[base + i] : 0;
    loc[i] = s; s += c;
  }
  part[t] = s;
  __syncthreads();
  for (int off = 1; off < 256; off <<= 1) {
    int v = part[t];
    if (t >= off) v += part[t - off];
    __syncthreads();
    part[t] = v;
    __syncthreads();
  }
  int excl = (t == 0) ? 0 : part[t - 1];
#pragma unroll
  for (int i = 0; i < 10; ++i) {
    if (base + i < N_ATOMS) {
      start[base + i] = excl + loc[i];
      fill[base + i]  = excl + loc[i];
    }
  }
  if (t == 255) start[N_ATOMS] = part[255];
}

__global__ __launch_bounds__(256) void k_fill(const int* __restrict__ centers,
                                              int* __restrict__ fill, int* __restrict__ elist) {
  int e = blockIdx.x * 256 + threadIdx.x;
  if (e >= N_EDGES) return;
  int pos = atomicAdd(&fill[centers[e]], 1);
  elist[pos] = e;
}

// ---------------- k_sph: per-edge S[q][lp] (bf16, shfl-friendly layout) ----------------
__global__ __launch_bounds__(256) void k_sph(
    const void* __restrict__ s0p, const void* __restrict__ s1p,
    const void* __restrict__ s2p, const void* __restrict__ s3p,
    const int* __restrict__ flag, const float* __restrict__ ws,
    unsigned short* __restrict__ S2v) {
  int tid = threadIdx.x;
  int e = blockIdx.x * 8 + (tid >> 5);
  int q = tid & 31;
  int isb = *flag;
  float sp0 = ldf(s0p, e, isb);
  float sp1[3], sp2[5], sp3[7];
#pragma unroll
  for (int m = 0; m < 3; ++m) sp1[m] = ldf(s1p, (long)e * 3 + m, isb);
#pragma unroll
  for (int m = 0; m < 5; ++m) sp2[m] = ldf(s2p, (long)e * 5 + m, isb);
#pragma unroll
  for (int m = 0; m < 7; ++m) sp3[m] = ldf(s3p, (long)e * 7 + m, isb);
  unsigned short* out = S2v + (size_t)e * 168;
  const float* U2 = ws + 52481;
  const float* U4 = ws + 52562;
  if (q < 9) {
    const float* r = U2 + q * 9;
    float s0 = r[0] * sp0;
    float s1 = r[1] * sp1[0] + r[2] * sp1[1] + r[3] * sp1[2];
    float s2 = r[4] * sp2[0] + r[5] * sp2[1] + r[6] * sp2[2] + r[7] * sp2[3] + r[8] * sp2[4];
    *reinterpret_cast<unsigned*>(out + 2 + 2 * q) = pk2(s0, s1);
    *reinterpret_cast<unsigned*>(out + 24 + 4 * q) = pk2(s0, s1);
    out[24 + 4 * q + 2] = f2bu(s2);
  }
  if (q < 25) {
    const float* r = U4 + q * 25;
    float w0 = r[0] * sp0;
    float w1 = r[1] * sp1[0] + r[2] * sp1[1] + r[3] * sp1[2];
    float w2 = r[4] * sp2[0] + r[5] * sp2[1] + r[6] * sp2[2] + r[7] * sp2[3] + r[8] * sp2[4];
    float w3 = 0.f;
#pragma unroll
    for (int m = 0; m < 7; ++m) w3 += r[9 + m] * sp3[m];
    *reinterpret_cast<unsigned*>(out + 64 + 4 * q)     = pk2(w0, w1);
    *reinterpret_cast<unsigned*>(out + 64 + 4 * q + 2) = pk2(w2, w3);
  }
  if (q == 31) out[0] = f2bu(ws[52480] * sp0);
}

// ---------------- k_radial4: MFMA GEMM -> rad2 (transposed bf16) ----------------
template <int l>
DEV void radial_body(const void* __restrict__ rb, const void* __restrict__ w2,
                     int isb, const float* __restrict__ ws, unsigned short* __restrict__ rad2,
                     int e0, int tid, unsigned short (*H)[72]) {
  constexpr int NM = (l == 0) ? 8 : (l == 1) ? 6 : (l == 2) ? 4 : 2;
  constexpr int K  = cK[l];
  const float* Wr1f = ws + cWR1[l];
  {
    int e  = e0 + (tid & 63);
    int j0 = (tid >> 6) * 16;
    float rbv[NM];
#pragma unroll
    for (int n = 0; n < NM; ++n) rbv[n] = ldf(rb, (long)e * NM + n, isb);
    float h[16];
#pragma unroll
    for (int j = 0; j < 16; ++j) h[j] = 0.f;
#pragma unroll
    for (int n = 0; n < NM; ++n) {
      float rv = rbv[n];
      const float4* wp = reinterpret_cast<const float4*>(Wr1f + n * 64 + j0);
#pragma unroll
      for (int qq = 0; qq < 4; ++qq) {
        float4 w = wp[qq];
        h[4 * qq + 0] += rv * w.x;
        h[4 * qq + 1] += rv * w.y;
        h[4 * qq + 2] += rv * w.z;
        h[4 * qq + 3] += rv * w.w;
      }
    }
    unsigned short* hrow = H[tid & 63];
#pragma unroll
    for (int j = 0; j < 16; j += 2) {
      float a0 = h[j], a1 = h[j + 1];
      a0 = a0 * (1.0f / (1.0f + __expf(-a0)));
      a1 = a1 * (1.0f / (1.0f + __expf(-a1)));
      *reinterpret_cast<unsigned*>(&hrow[j0 + j]) = pk2(a0, a1);
    }
  }
  __syncthreads();
  int wv = tid >> 6, lane = tid & 63;
  constexpr int NET = (l <= 1) ? 4 : (l == 2 ? 2 : 1);
  int c0, et0;
  bool active = true;
  if constexpr (l == 0)      { c0 = wv * 32;       et0 = 0; }
  else if constexpr (l == 1) { c0 = wv * 32;       et0 = 0; active = (wv < 3); }
  else if constexpr (l == 2) { c0 = (wv & 1) * 32; et0 = (wv >> 1) * 2; }
  else                       { c0 = 0;             et0 = wv; }
  if (!active) return;
  int ln15 = lane & 15, lhi = lane >> 4;
  short8 Bf[2][2];
#pragma unroll
  for (int ct = 0; ct < 2; ++ct)
#pragma unroll
    for (int ks = 0; ks < 2; ++ks) {
      int col = c0 + ct * 16 + ln15;
      int kb  = ks * 32 + lhi * 8;
#pragma unroll
      for (int i = 0; i < 8; ++i)
        Bf[ct][ks][i] = ldb(w2, (long)(kb + i) * K + col, isb);
    }
  f32x4 acc[NET][2];
#pragma unroll
  for (int et = 0; et < NET; ++et)
#pragma unroll
    for (int ct = 0; ct < 2; ++ct) acc[et][ct] = (f32x4){0.f, 0.f, 0.f, 0.f};
#pragma unroll
  for (int et = 0; et < NET; ++et) {
#pragma unroll
    for (int ks = 0; ks < 2; ++ks) {
      short8 Af = *reinterpret_cast<const short8*>(&H[(et0 + et) * 16 + ln15][ks * 32 + lhi * 8]);
      acc[et][0] = __builtin_amdgcn_mfma_f32_16x16x32_bf16(Af, Bf[0][ks], acc[et][0], 0, 0, 0);
      acc[et][1] = __builtin_amdgcn_mfma_f32_16x16x32_bf16(Af, Bf[1][ks], acc[et][1], 0, 0, 0);
    }
  }
  // store into rad2: channel c -> section lsec=3-(c>>5), lane-slot kk=c&31, lp-index = l
#pragma unroll
  for (int ct = 0; ct < 2; ++ct) {
    int c = c0 + ct * 16 + ln15;
    int lsec = 3 - (c >> 5);
    int kk = c & 31;
    int sec  = (lsec == 0) ? 0 : (lsec == 1) ? 32 : (lsec == 2) ? 96 : 224;
    int slot = (lsec >= 2) ? 4 : ((lsec == 1) ? 2 : 1);
    int off = sec + slot * kk + l;
#pragma unroll
    for (int et = 0; et < NET; ++et)
#pragma unroll
      for (int r = 0; r < 4; ++r) {
        int erow = (et0 + et) * 16 + lhi * 4 + r;
        rad2[(size_t)(e0 + erow) * 352 + off] = f2bu(acc[et][ct][r]);
      }
  }
}

__global__ __launch_bounds__(256) void k_radial4(
    const void* __restrict__ rb0, const void* __restrict__ rb1,
    const void* __restrict__ rb2, const void* __restrict__ rb3,
    const void* __restrict__ w20, const void* __restrict__ w21,
    const void* __restrict__ w22, const void* __restrict__ w23,
    const int* __restrict__ flag, const float* __restrict__ ws, unsigned short* __restrict__ rad2) {
  __shared__ __align__(16) unsigned short H[64][72];
  int isb = *flag;
  int l  = blockIdx.x / 625;
  int e0 = (blockIdx.x - l * 625) * 64;
  int tid = threadIdx.x;
  switch (l) {
    case 0: radial_body<0>(rb0, w20, isb, ws, rad2, e0, tid, H); break;
    case 1: radial_body<1>(rb1, w21, isb, ws, rad2, e0, tid, H); break;
    case 2: radial_body<2>(rb2, w22, isb, ws, rad2, e0, tid, H); break;
    default: radial_body<3>(rb3, w23, isb, ws, rad2, e0, tid, H); break;
  }
}

// ---------------- k_uncfeat -> unc2 (transposed per-lane bf16) ----------------
template <int l>
DEV void unc_one(int a, int k,
                 const void* __restrict__ f0, const void* __restrict__ f1,
                 const void* __restrict__ f2, const void* __restrict__ f3,
                 const float* __restrict__ ws, unsigned short* __restrict__ dst, int isb) {
  constexpr int T = cPL[l] + 1;
  constexpr int T2 = T * T;
  constexpr int M = (l + 1) * (l + 1);
  const float* U = ws + cUOF[l];
  const void* fps[4] = {f0, f1, f2, f3};
  float fc[M];
#pragma unroll
  for (int lp = 0; lp <= l; ++lp) {
    const void* fp = fps[lp];
#pragma unroll
    for (int mm = 0; mm < 2 * lp + 1; ++mm)
      fc[lp * lp + mm] = ldf(fp, ((long)a * (2 * lp + 1) + mm) * cK[lp] + cLO[l] + k, isb);
  }
  unsigned short* row = dst + cUO2[l] + cPW2[l] * k;
#pragma unroll
  for (int q = 0; q < T2; ++q) {
    float s = 0.f;
#pragma unroll
    for (int m = 0; m < M; ++m) s += U[q * T2 + m] * fc[m];
    row[q] = f2bu(s);
  }
}

__global__ __launch_bounds__(64) void k_uncfeat(
    const void* __restrict__ f0, const void* __restrict__ f1,
    const void* __restrict__ f2, const void* __restrict__ f3,
    const int* __restrict__ flag, const float* __restrict__ ws, unsigned short* __restrict__ unc2) {
  int a = blockIdx.x * 2 + (threadIdx.x >> 5);
  int k = threadIdx.x & 31;
  if (a >= N_ATOMS) return;
  int isb = *flag;
  unsigned short* dst = unc2 + (size_t)a * 2080;
  unc_one<0>(a, k, f0, f1, f2, f3, ws, dst, isb);
  unc_one<1>(a, k, f0, f1, f2, f3, ws, dst, isb);
  unc_one<2>(a, k, f0, f1, f2, f3, ws, dst, isb);
  unc_one<3>(a, k, f0, f1, f2, f3, ws, dst, isb);
}

// ---------------- k_edge4: CSR accumulation, packed operands ----------------
__global__ __launch_bounds__(256) void k_edge4(
    const int* __restrict__ start, const int* __restrict__ elist,
    const int* __restrict__ neighbors,
    const float* __restrict__ ws,
    const unsigned short* __restrict__ rad2,
    const unsigned short* __restrict__ S2v,
    const unsigned short* __restrict__ unc2,
    unsigned short* __restrict__ ccg) {
  int a = blockIdx.x;
  int tid = threadIdx.x;
  int wv = tid >> 6;
  int k = tid & 31;
  int strm = tid >> 5;
  int beg = start[a], end = start[a + 1];

  float acc[44];
#pragma unroll
  for (int j = 0; j < 44; ++j) acc[j] = 0.f;

  int q9  = (k < 9)  ? k : 8;
  int q25 = (k < 25) ? k : 24;

  for (int i = beg + strm; i < end; i += 8) {
    int e = elist[i];
    int ne = neighbors[e];
    const unsigned short* rr = rad2 + (size_t)e * 352;
    const unsigned short* sr = S2v + (size_t)e * 168;
    const unsigned short* fr = unc2 + (size_t)ne * 2080;

    // packed rv loads
    float rv0 = bu2f(rr[k]);
    unsigned u1 = *reinterpret_cast<const unsigned*>(rr + 32 + 2 * k);
    uint2 u2v = *reinterpret_cast<const uint2*>(rr + 96 + 4 * k);
    uint2 u3v = *reinterpret_cast<const uint2*>(rr + 224 + 4 * k);
    float rv1[2] = { lo2f(u1), hi2f(u1) };
    float rv2[3] = { lo2f(u2v.x), hi2f(u2v.x), lo2f(u2v.y) };
    float rv3[4] = { lo2f(u3v.x), hi2f(u3v.x), lo2f(u3v.y), hi2f(u3v.y) };

    // packed S loads (lane k plays role q)
    float s0v = bu2f(sr[0]);
    unsigned su1 = *reinterpret_cast<const unsigned*>(sr + 2 + 2 * q9);
    uint2 su2 = *reinterpret_cast<const uint2*>(sr + 24 + 4 * q9);
    uint2 su3 = *reinterpret_cast<const uint2*>(sr + 64 + 4 * q25);
    float S1[2] = { lo2f(su1), hi2f(su1) };
    float S2a[3] = { lo2f(su2.x), hi2f(su2.x), lo2f(su2.y) };
    float S3a[4] = { lo2f(su3.x), hi2f(su3.x), lo2f(su3.y), hi2f(su3.y) };

    // ---- l0 ----
    acc[0] += rv0 * s0v * bu2f(fr[k]);

    // ---- l1 ----
    {
      uint4 fu = *reinterpret_cast<const uint4*>(fr + 32 + 16 * k);
      float F[9];
      F[0] = lo2f(fu.x); F[1] = hi2f(fu.x); F[2] = lo2f(fu.y); F[3] = hi2f(fu.y);
      F[4] = lo2f(fu.z); F[5] = hi2f(fu.z); F[6] = lo2f(fu.w); F[7] = hi2f(fu.w);
      F[8] = bu2f(fr[32 + 16 * k + 8]);
      float V[9];
#pragma unroll
      for (int q = 0; q < 9; ++q)
        V[q] = rv1[0] * __shfl(S1[0], q, 32) + rv1[1] * __shfl(S1[1], q, 32);
#pragma unroll
      for (int i3 = 0; i3 < 3; ++i3)
#pragma unroll
        for (int j3 = 0; j3 < 3; ++j3)
          acc[1 + i3 * 3 + j3] += V[i3 * 3 + 0] * F[0 + j3] + V[i3 * 3 + 1] * F[3 + j3] + V[i3 * 3 + 2] * F[6 + j3];
    }
    // ---- l2 ----
    {
      uint4 fu = *reinterpret_cast<const uint4*>(fr + 544 + 16 * k);
      float F[9];
      F[0] = lo2f(fu.x); F[1] = hi2f(fu.x); F[2] = lo2f(fu.y); F[3] = hi2f(fu.y);
      F[4] = lo2f(fu.z); F[5] = hi2f(fu.z); F[6] = lo2f(fu.w); F[7] = hi2f(fu.w);
      F[8] = bu2f(fr[544 + 16 * k + 8]);
      float V[9];
#pragma unroll
      for (int q = 0; q < 9; ++q)
        V[q] = rv2[0] * __shfl(S2a[0], q, 32) + rv2[1] * __shfl(S2a[1], q, 32)
             + rv2[2] * __shfl(S2a[2], q, 32);
#pragma unroll
      for (int i3 = 0; i3 < 3; ++i3)
#pragma unroll
        for (int j3 = 0; j3 < 3; ++j3)
          acc[10 + i3 * 3 + j3] += V[i3 * 3 + 0] * F[0 + j3] + V[i3 * 3 + 1] * F[3 + j3] + V[i3 * 3 + 2] * F[6 + j3];
    }
    // ---- l3 ----
    {
      const unsigned short* fb = fr + 1056 + 32 * k;
      uint4 fa = *reinterpret_cast<const uint4*>(fb);
      uint4 fbu = *reinterpret_cast<const uint4*>(fb + 8);
      uint4 fcu = *reinterpret_cast<const uint4*>(fb + 16);
      float F[25];
      F[0] = lo2f(fa.x);  F[1] = hi2f(fa.x);  F[2] = lo2f(fa.y);  F[3] = hi2f(fa.y);
      F[4] = lo2f(fa.z);  F[5] = hi2f(fa.z);  F[6] = lo2f(fa.w);  F[7] = hi2f(fa.w);
      F[8] = lo2f(fbu.x); F[9] = hi2f(fbu.x); F[10] = lo2f(fbu.y); F[11] = hi2f(fbu.y);
      F[12] = lo2f(fbu.z); F[13] = hi2f(fbu.z); F[14] = lo2f(fbu.w); F[15] = hi2f(fbu.w);
      F[16] = lo2f(fcu.x); F[17] = hi2f(fcu.x); F[18] = lo2f(fcu.y); F[19] = hi2f(fcu.y);
      F[20] = lo2f(fcu.z); F[21] = hi2f(fcu.z); F[22] = lo2f(fcu.w); F[23] = hi2f(fcu.w);
      F[24] = bu2f(fb[24]);
      float V[25];
#pragma unroll
      for (int q = 0; q < 25; ++q)
        V[q] = rv3[0] * __shfl(S3a[0], q, 32) + rv3[1] * __shfl(S3a[1], q, 32)
             + rv3[2] * __shfl(S3a[2], q, 32) + rv3[3] * __shfl(S3a[3], q, 32);
#pragma unroll
      for (int i5 = 0; i5 < 5; ++i5)
#pragma unroll
        for (int j5 = 0; j5 < 5; ++j5) {
          float c = V[i5 * 5 + 0] * F[0 + j5] + V[i5 * 5 + 1] * F[5 + j5]
                  + V[i5 * 5 + 2] * F[10 + j5] + V[i5 * 5 + 3] * F[15 + j5]
                  + V[i5 * 5 + 4] * F[20 + j5];
          acc[19 + i5 * 5 + j5] += c;
        }
    }
  }
#pragma unroll
  for (int j = 0; j < 44; ++j) acc[j] += __shfl_xor(acc[j], 32);

  __shared__ float buf[4][1408];
  if ((tid & 32) == 0) {
#pragma unroll
    for (int l = 0; l < 4; ++l) {
      int T2 = (cPL[l] + 1) * (cPL[l] + 1);
      for (int q = 0; q < T2; ++q)
        buf[wv][cSOFF[l] + q * 32 + k] = acc[cAOF[l] + q];
    }
  }
  __syncthreads();
  for (int idx = tid; idx < 1408; idx += 256)
    buf[0][idx] = (buf[0][idx] + buf[1][idx]) + (buf[2][idx] + buf[3][idx]);
  __syncthreads();
  unsigned short* crow = ccg + (size_t)a * 960;
  for (int idx = tid; idx < 960; idx += 256) {
    int kk = idx & 31, combo = idx >> 5;
    int l = c_tl[combo], mm = c_tmm[combo], s = c_ts[combo];
    int lp = l + s;
    int Ts = c_pl_r[lp] + 1;
    int Ts2 = Ts * Ts;
    const float* U = ws + c_uof_r[lp];
    const float* pr = &buf[0][c_soff_r[lp]];
    int m = l * l + mm;
    float sacc = 0.f;
    for (int q = 0; q < Ts2; ++q) sacc += U[q * Ts2 + m] * pr[q * 32 + kk];
    crow[idx] = f2bu(sacc);
  }
}

// ---------------- k_out2: MFMA GEMM  out = feats + concat @ Wl ----------------
template <int l>
DEV void out_body(const void* __restrict__ ft, const void* __restrict__ wl,
                  const unsigned short* __restrict__ ccg, void* __restrict__ out,
                  int rt, int tid, int isb) {
  constexpr int NMM = 2 * l + 1;
  constexpr int K   = cK[l];
  constexpr int NKS = K / 32;
  constexpr int M   = N_ATOMS * NMM;
  constexpr int NET = (l <= 1) ? 4 : (l == 2 ? 2 : 1);
  int wv = tid >> 6, lane = tid & 63;
  int c0, et0;
  bool active = true;
  if constexpr (l == 0)      { c0 = wv * 32;       et0 = 0; }
  else if constexpr (l == 1) { c0 = wv * 32;       et0 = 0; active = (wv < 3); }
  else if constexpr (l == 2) { c0 = (wv & 1) * 32; et0 = (wv >> 1) * 2; }
  else                       { c0 = 0;             et0 = wv; }
  if (!active) return;
  int ln15 = lane & 15, lhi = lane >> 4;
  int r0 = rt * 64;
  short8 Bf[2][NKS];
#pragma unroll
  for (int ct = 0; ct < 2; ++ct)
#pragma unroll
    for (int ks = 0; ks < NKS; ++ks) {
      int col = c0 + ct * 16 + ln15;
      int kb  = ks * 32 + lhi * 8;
#pragma unroll
      for (int i = 0; i < 8; ++i)
        Bf[ct][ks][i] = ldb(wl, (long)(kb + i) * K + col, isb);
    }
  long abase[NET];
#pragma unroll
  for (int et = 0; et < NET; ++et) {
    int R = r0 + (et0 + et) * 16 + ln15;
    if (R >= M) R = M - 1;
    int a = R / NMM, mm = R - a * NMM;
    abase[et] = (long)a * 960 + cCB[l] + (long)mm * K;
  }
  f32x4 acc[NET][2];
#pragma unroll
  for (int et = 0; et < NET; ++et)
#pragma unroll
    for (int ct = 0; ct < 2; ++ct) acc[et][ct] = (f32x4){0.f, 0.f, 0.f, 0.f};
#pragma unroll
  for (int et = 0; et < NET; ++et) {
#pragma unroll
    for (int ks = 0; ks < NKS; ++ks) {
      short8 Af = *reinterpret_cast<const short8*>(&ccg[abase[et] + ks * 32 + lhi * 8]);
      acc[et][0] = __builtin_amdgcn_mfma_f32_16x16x32_bf16(Af, Bf[0][ks], acc[et][0], 0, 0, 0);
      acc[et][1] = __builtin_amdgcn_mfma_f32_16x16x32_bf16(Af, Bf[1][ks], acc[et][1], 0, 0, 0);
    }
  }
#pragma unroll
  for (int et = 0; et < NET; ++et)
#pragma unroll
    for (int ct = 0; ct < 2; ++ct)
#pragma unroll
      for (int r = 0; r < 4; ++r) {
        int R = r0 + (et0 + et) * 16 + lhi * 4 + r;
        if (R < M) {
          int col = c0 + ct * 16 + ln15;
          long o = (long)R * K + col;
          stf(out, cOUT[l] + o, ldf(ft, o, isb) + acc[et][ct][r], isb);
        }
      }
}

__global__ __launch_bounds__(256) void k_out2(
    const void* __restrict__ f0, const void* __restrict__ f1,
    const void* __restrict__ f2, const void* __restrict__ f3,
    const void* __restrict__ wl0, const void* __restrict__ wl1,
    const void* __restrict__ wl2, const void* __restrict__ wl3,
    const int* __restrict__ flag, const unsigned short* __restrict__ ccg,
    void* __restrict__ out) {
  int isb = *flag;
  int b = blockIdx.x;
  int tid = threadIdx.x;
  if      (b < 40)  out_body<0>(f0, wl0, ccg, out, b,       tid, isb);
  else if (b < 158) out_body<1>(f1, wl1, ccg, out, b - 40,  tid, isb);
  else if (b < 354) out_body<2>(f2, wl2, ccg, out, b - 158, tid, isb);
  else              out_body<3>(f3, wl3, ccg, out, b - 354, tid, isb);
}

// ---------------- launch ----------------
extern "C" void kernel_launch(void* const* d_in, const int* in_sizes, int n_in,
                              void* d_out, int out_size, void* d_ws, size_t ws_size,
                              hipStream_t stream) {
  (void)n_in; (void)out_size; (void)ws_size;
  bool dictord = (in_sizes[1] == 40000);
  const void* rb[4]; const void* sph[4]; const void* ft[4];
  const void *w1[4], *w2[4], *wl[4];
  for (int l = 0; l < 4; ++l) {
    if (dictord) {
      rb[l]  = d_in[3 * l + 0];
      sph[l] = d_in[3 * l + 1];
      ft[l]  = d_in[3 * l + 2];
      w1[l]  = d_in[17 + 3 * l];
      w2[l]  = d_in[18 + 3 * l];
      wl[l]  = d_in[19 + 3 * l];
    } else {
      rb[l]  = d_in[l];
      sph[l] = d_in[4 + l];
      ft[l]  = d_in[8 + l];
      w1[l]  = d_in[17 + l];
      w2[l]  = d_in[21 + l];
      wl[l]  = d_in[25 + l];
    }
  }
  const int* centers   = (const int*)d_in[12];
  const int* neighbors = (const int*)d_in[13];
  const void* u0 = d_in[14];
  const void* u2 = d_in[15];
  const void* u4 = d_in[16];

  float* ws   = (float*)d_ws;
  int*   flag = (int*)(ws + FLAG_OFF);
  unsigned short* rad2 = (unsigned short*)(ws + RAD2_OFF);
  unsigned short* S2v  = (unsigned short*)(ws + S2_OFF);
  unsigned short* unc2 = (unsigned short*)(ws + UNC2_OFF);
  unsigned short* ccg  = (unsigned short*)(ws + CCG_OFF);
  int*   cnt   = (int*)(ws + CNT_OFF);
  int*   start = (int*)(ws + START_OFF);
  int*   fill  = (int*)(ws + FILL_OFF);
  int*   elist = (int*)(ws + ELIST_OFF);

  hipMemsetAsync(cnt, 0, N_ATOMS * sizeof(int), stream);
  k_detect<<<1, 64, 0, stream>>>(w2[0], flag);
  k_count<<<(N_EDGES + 255) / 256, 256, 0, stream>>>(centers, cnt);
  k_scan<<<1, 256, 0, stream>>>(cnt, start, fill);
  k_fill<<<(N_EDGES + 255) / 256, 256, 0, stream>>>(centers, fill, elist);
  k_prep<<<208, 256, 0, stream>>>(w1[0], w1[1], w1[2], w1[3],
                                  w2[0], w2[1], w2[2], w2[3],
                                  wl[0], wl[1], wl[2], wl[3],
                                  u0, u2, u4, flag, ws);
  k_sph<<<5000, 256, 0, stream>>>(sph[0], sph[1], sph[2], sph[3], flag, ws, S2v);
  k_radial4<<<2500, 256, 0, stream>>>(rb[0], rb[1], rb[2], rb[3],
                                      w2[0], w2[1], w2[2], w2[3], flag, ws, rad2);
  k_uncfeat<<<N_ATOMS / 2, 64, 0, stream>>>(ft[0], ft[1], ft[2], ft[3], flag, ws, unc2);
  k_edge4<<<N_ATOMS, 256, 0, stream>>>(start, elist, neighbors, ws, rad2, S2v, unc2, ccg);
  k_out2<<<628, 256, 0, stream>>>(ft[0], ft[1], ft[2], ft[3],
                                  wl[0], wl[1], wl[2], wl[3], flag, ccg, (void*)d_out);
}

// Round 10
// 207.410 us; speedup vs baseline: 1.2428x; 1.2428x over previous
//
#include <hip/hip_runtime.h>
#include <hip/hip_bf16.h>

typedef __hip_bfloat16 bf16;
using short8 = __attribute__((ext_vector_type(8))) short;
using f32x4  = __attribute__((ext_vector_type(4))) float;

#define DEV static __device__ __forceinline__

DEV float b2f(bf16 x) { return __bfloat162float(x); }
DEV float ldf(const void* p, long i, int isb) {
  return isb ? b2f(((const bf16*)p)[i]) : ((const float*)p)[i];
}
DEV void stf(void* p, long i, float v, int isb) {
  if (isb) ((bf16*)p)[i] = __float2bfloat16(v);
  else     ((float*)p)[i] = v;
}
DEV unsigned short f2bu(float f) {
  union { bf16 h; unsigned short u; } v; v.h = __float2bfloat16(f); return v.u;
}
DEV float bu2f(unsigned short u) {
  union { unsigned x; float f; } v; v.x = ((unsigned)u) << 16; return v.f;
}
DEV float lo2f(unsigned u) { union { unsigned x; float f; } v; v.x = u << 16; return v.f; }
DEV float hi2f(unsigned u) { union { unsigned x; float f; } v; v.x = u & 0xFFFF0000u; return v.f; }
DEV unsigned pk2(float a, float b) { return (unsigned)f2bu(a) | ((unsigned)f2bu(b) << 16); }
DEV short ldb(const void* p, long i, int isb) {
  if (isb) return ((const short*)p)[i];
  union { bf16 h; short s; } v; v.h = __float2bfloat16(((const float*)p)[i]); return v.s;
}

// ---- problem constants ----
#define N_ATOMS 2500
#define N_EDGES 40000

constexpr int cK[4]    = {128, 96, 64, 32};
constexpr int cPL[4]   = {0, 2, 2, 4};
constexpr int cLO[4]   = {96, 64, 32, 0};
constexpr int cSOFF[4] = {0, 32, 320, 608};
constexpr int cAOF[4]  = {0, 1, 10, 19};
// ws float-offsets
constexpr int cWR1[4] = {0, 512, 896, 1152};
constexpr int cWR2[4] = {1280, 9472, 15616, 19712};
constexpr int cWL[4]  = {21760, 38144, 47360, 51456};
constexpr int cUOF[4] = {52480, 52481, 52481, 52562};
constexpr int FLAG_OFF = 53240;
// rad2: [e][352 ushorts]
constexpr int RAD2_OFF = 53248;                        // 40000*176 floats
constexpr int S2_OFF   = RAD2_OFF + N_EDGES * 176;     // 7,093,248 ; [e][168 ushorts]
// unc3: [a][768 dwords]: sec0@0, sec1@32 (5 rows), sec2@192 (5 rows), sec3@352 (13 rows); row=32 dwords
constexpr int UNC3_OFF = S2_OFF + N_EDGES * 84;        // 10,453,248
constexpr int CCG_OFF  = UNC3_OFF + N_ATOMS * 768;     // 12,373,248
constexpr int CSR_OFF   = CCG_OFF + N_ATOMS * 480;     // 13,573,248
constexpr int CNT_OFF   = CSR_OFF;
constexpr int START_OFF = CSR_OFF + 2500;
constexpr int FILL_OFF  = CSR_OFF + 5008;
constexpr int ELIST_OFF = CSR_OFF + 7512;

constexpr int cCB[4]  = {0, 128, 416, 736};
constexpr int cOUT[4] = {0, 320000, 1040000, 1840000};

__device__ const int c_tl[30]  = {0,0,0,0, 1,1,1,1,1,1,1,1,1, 2,2,2,2,2,2,2,2,2,2, 3,3,3,3,3,3,3};
__device__ const int c_tmm[30] = {0,0,0,0, 0,0,0,1,1,1,2,2,2, 0,0,1,1,2,2,3,3,4,4, 0,1,2,3,4,5,6};
__device__ const int c_ts[30]  = {0,1,2,3, 0,1,2,0,1,2,0,1,2, 0,1,0,1,0,1,0,1,0,1, 0,0,0,0,0,0,0};
__device__ const int c_soff_r[4] = {0, 32, 320, 608};
__device__ const int c_uof_r[4]  = {52480, 52481, 52481, 52562};
__device__ const int c_pl_r[4]   = {0, 2, 2, 4};

// ---------------- k_detect (verbatim R7) ----------------
__global__ void k_detect(const void* __restrict__ w2_0, int* __restrict__ flag) {
  if (threadIdx.x != 0 || blockIdx.x != 0) return;
  const unsigned* w = (const unsigned*)w2_0;
  int ok = 0;
  for (int i = 0; i < 512; ++i) {
    unsigned lo = w[i] & 0xFFFFu;
    unsigned e = (lo >> 7) & 0xFFu;
    if (lo == 0u || (e >= 100u && e <= 140u)) ok++;
  }
  *flag = (ok >= 256) ? 1 : 0;
}

// ---------------- k_prep (verbatim R7) ----------------
__global__ __launch_bounds__(256) void k_prep(
    const void* __restrict__ w10, const void* __restrict__ w11, const void* __restrict__ w12, const void* __restrict__ w13,
    const void* __restrict__ w20, const void* __restrict__ w21, const void* __restrict__ w22, const void* __restrict__ w23,
    const void* __restrict__ wl0, const void* __restrict__ wl1, const void* __restrict__ wl2, const void* __restrict__ wl3,
    const void* __restrict__ u0, const void* __restrict__ u2, const void* __restrict__ u4,
    const int* __restrict__ flag, float* __restrict__ ws) {
  int i = blockIdx.x * 256 + threadIdx.x;
  if (i >= 53187) return;
  int isb = *flag;
  const void* src; int base;
  if      (i < 512)   { src = w10; base = 0; }
  else if (i < 896)   { src = w11; base = 512; }
  else if (i < 1152)  { src = w12; base = 896; }
  else if (i < 1280)  { src = w13; base = 1152; }
  else if (i < 9472)  { src = w20; base = 1280; }
  else if (i < 15616) { src = w21; base = 9472; }
  else if (i < 19712) { src = w22; base = 15616; }
  else if (i < 21760) { src = w23; base = 19712; }
  else if (i < 38144) { src = wl0; base = 21760; }
  else if (i < 47360) { src = wl1; base = 38144; }
  else if (i < 51456) { src = wl2; base = 47360; }
  else if (i < 52480) { src = wl3; base = 51456; }
  else if (i < 52481) { src = u0;  base = 52480; }
  else if (i < 52562) { src = u2;  base = 52481; }
  else                { src = u4;  base = 52562; }
  ws[i] = ldf(src, i - base, isb);
}

// ---------------- CSR build (verbatim R7) ----------------
__global__ __launch_bounds__(256) void k_count(const int* __restrict__ centers, int* __restrict__ cnt) {
  int e = blockIdx.x * 256 + threadIdx.x;
  if (e < N_EDGES) atomicAdd(&cnt[centers[e]], 1);
}

__global__ __launch_bounds__(256) void k_scan(const int* __restrict__ cnt,
                                              int* __restrict__ start, int* __restrict__ fill) {
  __shared__ int part[256];
  int t = threadIdx.x;
  int loc[10];
  int s = 0;
  int base = t * 10;
#pragma unroll
  for (int i = 0; i < 10; ++i) {
    int c = (base + i < N_ATOMS) ? cnt[base + i] : 0;
    loc[i] = s; s += c;
  }
  part[t] = s;
  __syncthreads();
  for (int off = 1; off < 256; off <<= 1) {
    int v = part[t];
    if (t >= off) v += part[t - off];
    __syncthreads();
    part[t] = v;
    __syncthreads();
  }
  int excl = (t == 0) ? 0 : part[t - 1];
#pragma unroll
  for (int i = 0; i < 10; ++i) {
    if (base + i < N_ATOMS) {
      start[base + i] = excl + loc[i];
      fill[base + i]  = excl + loc[i];
    }
  }
  if (t == 255) start[N_ATOMS] = part[255];
}

__global__ __launch_bounds__(256) void k_fill(const int* __restrict__ centers,
                                              int* __restrict__ fill, int* __restrict__ elist) {
  int e = blockIdx.x * 256 + threadIdx.x;
  if (e >= N_EDGES) return;
  int pos = atomicAdd(&fill[centers[e]], 1);
  elist[pos] = e;
}

// ---------------- k_sph (verbatim R7) ----------------
__global__ __launch_bounds__(256) void k_sph(
    const void* __restrict__ s0p, const void* __restrict__ s1p,
    const void* __restrict__ s2p, const void* __restrict__ s3p,
    const int* __restrict__ flag, const float* __restrict__ ws,
    unsigned short* __restrict__ S2v) {
  int tid = threadIdx.x;
  int e = blockIdx.x * 8 + (tid >> 5);
  int q = tid & 31;
  int isb = *flag;
  float sp0 = ldf(s0p, e, isb);
  float sp1[3], sp2[5], sp3[7];
#pragma unroll
  for (int m = 0; m < 3; ++m) sp1[m] = ldf(s1p, (long)e * 3 + m, isb);
#pragma unroll
  for (int m = 0; m < 5; ++m) sp2[m] = ldf(s2p, (long)e * 5 + m, isb);
#pragma unroll
  for (int m = 0; m < 7; ++m) sp3[m] = ldf(s3p, (long)e * 7 + m, isb);
  unsigned short* out = S2v + (size_t)e * 168;
  const float* U2 = ws + 52481;
  const float* U4 = ws + 52562;
  if (q < 9) {
    const float* r = U2 + q * 9;
    float s0 = r[0] * sp0;
    float s1 = r[1] * sp1[0] + r[2] * sp1[1] + r[3] * sp1[2];
    float s2 = r[4] * sp2[0] + r[5] * sp2[1] + r[6] * sp2[2] + r[7] * sp2[3] + r[8] * sp2[4];
    *reinterpret_cast<unsigned*>(out + 2 + 2 * q) = pk2(s0, s1);
    *reinterpret_cast<unsigned*>(out + 24 + 4 * q) = pk2(s0, s1);
    out[24 + 4 * q + 2] = f2bu(s2);
    out[24 + 4 * q + 3] = 0;
  }
  if (q < 25) {
    const float* r = U4 + q * 25;
    float w0 = r[0] * sp0;
    float w1 = r[1] * sp1[0] + r[2] * sp1[1] + r[3] * sp1[2];
    float w2 = r[4] * sp2[0] + r[5] * sp2[1] + r[6] * sp2[2] + r[7] * sp2[3] + r[8] * sp2[4];
    float w3 = 0.f;
#pragma unroll
    for (int m = 0; m < 7; ++m) w3 += r[9 + m] * sp3[m];
    *reinterpret_cast<unsigned*>(out + 64 + 4 * q)     = pk2(w0, w1);
    *reinterpret_cast<unsigned*>(out + 64 + 4 * q + 2) = pk2(w2, w3);
  }
  if (q == 31) out[0] = f2bu(ws[52480] * sp0);
}

// ---------------- k_radial4 (verbatim R7, rad2 bf16 transposed) ----------------
template <int l>
DEV void radial_body(const void* __restrict__ rb, const void* __restrict__ w2,
                     int isb, const float* __restrict__ ws, unsigned short* __restrict__ rad2,
                     int e0, int tid, unsigned short (*H)[72]) {
  constexpr int NM = (l == 0) ? 8 : (l == 1) ? 6 : (l == 2) ? 4 : 2;
  constexpr int K  = cK[l];
  const float* Wr1f = ws + cWR1[l];
  {
    int e  = e0 + (tid & 63);
    int j0 = (tid >> 6) * 16;
    float rbv[NM];
#pragma unroll
    for (int n = 0; n < NM; ++n) rbv[n] = ldf(rb, (long)e * NM + n, isb);
    float h[16];
#pragma unroll
    for (int j = 0; j < 16; ++j) h[j] = 0.f;
#pragma unroll
    for (int n = 0; n < NM; ++n) {
      float rv = rbv[n];
      const float4* wp = reinterpret_cast<const float4*>(Wr1f + n * 64 + j0);
#pragma unroll
      for (int qq = 0; qq < 4; ++qq) {
        float4 w = wp[qq];
        h[4 * qq + 0] += rv * w.x;
        h[4 * qq + 1] += rv * w.y;
        h[4 * qq + 2] += rv * w.z;
        h[4 * qq + 3] += rv * w.w;
      }
    }
    unsigned short* hrow = H[tid & 63];
#pragma unroll
    for (int j = 0; j < 16; j += 2) {
      float a0 = h[j], a1 = h[j + 1];
      a0 = a0 * (1.0f / (1.0f + __expf(-a0)));
      a1 = a1 * (1.0f / (1.0f + __expf(-a1)));
      *reinterpret_cast<unsigned*>(&hrow[j0 + j]) = pk2(a0, a1);
    }
  }
  __syncthreads();
  int wv = tid >> 6, lane = tid & 63;
  constexpr int NET = (l <= 1) ? 4 : (l == 2 ? 2 : 1);
  int c0, et0;
  bool active = true;
  if constexpr (l == 0)      { c0 = wv * 32;       et0 = 0; }
  else if constexpr (l == 1) { c0 = wv * 32;       et0 = 0; active = (wv < 3); }
  else if constexpr (l == 2) { c0 = (wv & 1) * 32; et0 = (wv >> 1) * 2; }
  else                       { c0 = 0;             et0 = wv; }
  if (!active) return;
  int ln15 = lane & 15, lhi = lane >> 4;
  short8 Bf[2][2];
#pragma unroll
  for (int ct = 0; ct < 2; ++ct)
#pragma unroll
    for (int ks = 0; ks < 2; ++ks) {
      int col = c0 + ct * 16 + ln15;
      int kb  = ks * 32 + lhi * 8;
#pragma unroll
      for (int i = 0; i < 8; ++i)
        Bf[ct][ks][i] = ldb(w2, (long)(kb + i) * K + col, isb);
    }
  f32x4 acc[NET][2];
#pragma unroll
  for (int et = 0; et < NET; ++et)
#pragma unroll
    for (int ct = 0; ct < 2; ++ct) acc[et][ct] = (f32x4){0.f, 0.f, 0.f, 0.f};
#pragma unroll
  for (int et = 0; et < NET; ++et) {
#pragma unroll
    for (int ks = 0; ks < 2; ++ks) {
      short8 Af = *reinterpret_cast<const short8*>(&H[(et0 + et) * 16 + ln15][ks * 32 + lhi * 8]);
      acc[et][0] = __builtin_amdgcn_mfma_f32_16x16x32_bf16(Af, Bf[0][ks], acc[et][0], 0, 0, 0);
      acc[et][1] = __builtin_amdgcn_mfma_f32_16x16x32_bf16(Af, Bf[1][ks], acc[et][1], 0, 0, 0);
    }
  }
#pragma unroll
  for (int ct = 0; ct < 2; ++ct) {
    int c = c0 + ct * 16 + ln15;
    int lsec = 3 - (c >> 5);
    int kk = c & 31;
    int sec  = (lsec == 0) ? 0 : (lsec == 1) ? 32 : (lsec == 2) ? 96 : 224;
    int slot = (lsec >= 2) ? 4 : ((lsec == 1) ? 2 : 1);
    int off = sec + slot * kk + l;
#pragma unroll
    for (int et = 0; et < NET; ++et)
#pragma unroll
      for (int r = 0; r < 4; ++r) {
        int erow = (et0 + et) * 16 + lhi * 4 + r;
        rad2[(size_t)(e0 + erow) * 352 + off] = f2bu(acc[et][ct][r]);
      }
  }
}

__global__ __launch_bounds__(256) void k_radial4(
    const void* __restrict__ rb0, const void* __restrict__ rb1,
    const void* __restrict__ rb2, const void* __restrict__ rb3,
    const void* __restrict__ w20, const void* __restrict__ w21,
    const void* __restrict__ w22, const void* __restrict__ w23,
    const int* __restrict__ flag, const float* __restrict__ ws, unsigned short* __restrict__ rad2) {
  __shared__ __align__(16) unsigned short H[64][72];
  int isb = *flag;
  int l  = blockIdx.x / 625;
  int e0 = (blockIdx.x - l * 625) * 64;
  int tid = threadIdx.x;
  switch (l) {
    case 0: radial_body<0>(rb0, w20, isb, ws, rad2, e0, tid, H); break;
    case 1: radial_body<1>(rb1, w21, isb, ws, rad2, e0, tid, H); break;
    case 2: radial_body<2>(rb2, w22, isb, ws, rad2, e0, tid, H); break;
    default: radial_body<3>(rb3, w23, isb, ws, rad2, e0, tid, H); break;
  }
}

// ---------------- k_uncfeat -> unc3 (dword-pair packed, [sec][q2][k]) ----------------
template <int l>
DEV void unc_one(int a, int k,
                 const void* __restrict__ f0, const void* __restrict__ f1,
                 const void* __restrict__ f2, const void* __restrict__ f3,
                 const float* __restrict__ ws, unsigned* __restrict__ dst, int isb) {
  constexpr int T2 = (cPL[l] + 1) * (cPL[l] + 1);
  constexpr int M = (l + 1) * (l + 1);
  constexpr int NB = (T2 + 1) / 2;
  constexpr int base = (l == 0) ? 0 : (l == 1) ? 32 : (l == 2) ? 192 : 352;
  const float* U = ws + cUOF[l];
  const void* fps[4] = {f0, f1, f2, f3};
  float fc[M];
#pragma unroll
  for (int lp = 0; lp <= l; ++lp) {
    const void* fp = fps[lp];
#pragma unroll
    for (int mm = 0; mm < 2 * lp + 1; ++mm)
      fc[lp * lp + mm] = ldf(fp, ((long)a * (2 * lp + 1) + mm) * cK[lp] + cLO[l] + k, isb);
  }
  float v[T2];
#pragma unroll
  for (int q = 0; q < T2; ++q) {
    float s = 0.f;
#pragma unroll
    for (int m = 0; m < M; ++m) s += U[q * T2 + m] * fc[m];
    v[q] = s;
  }
#pragma unroll
  for (int q2 = 0; q2 < NB; ++q2) {
    float a0 = v[2 * q2];
    float a1 = (2 * q2 + 1 < T2) ? v[2 * q2 + 1] : 0.f;
    dst[base + q2 * 32 + k] = pk2(a0, a1);
  }
}

__global__ __launch_bounds__(64) void k_uncfeat(
    const void* __restrict__ f0, const void* __restrict__ f1,
    const void* __restrict__ f2, const void* __restrict__ f3,
    const int* __restrict__ flag, const float* __restrict__ ws, unsigned* __restrict__ unc3) {
  int a = blockIdx.x * 2 + (threadIdx.x >> 5);
  int k = threadIdx.x & 31;
  if (a >= N_ATOMS) return;
  int isb = *flag;
  unsigned* dst = unc3 + (size_t)a * 768;
  unc_one<0>(a, k, f0, f1, f2, f3, ws, dst, isb);
  unc_one<1>(a, k, f0, f1, f2, f3, ws, dst, isb);
  unc_one<2>(a, k, f0, f1, f2, f3, ws, dst, isb);
  unc_one<3>(a, k, f0, f1, f2, f3, ws, dst, isb);
}

// ---------------- k_edge5: packed loads + packed shfl + prefetch ----------------
__global__ __launch_bounds__(256) void k_edge5(
    const int* __restrict__ start, const int* __restrict__ elist,
    const int* __restrict__ neighbors, const float* __restrict__ ws,
    const unsigned short* __restrict__ rad2, const unsigned short* __restrict__ S2v,
    const unsigned* __restrict__ unc3, unsigned short* __restrict__ ccg) {
  int a = blockIdx.x;
  int tid = threadIdx.x;
  int wv = tid >> 6;
  int k = tid & 31;
  int strm = tid >> 5;
  int beg = start[a], end = start[a + 1];
  int q9  = (k < 9)  ? k : 8;
  int q25 = (k < 25) ? k : 24;

  float acc[44];
#pragma unroll
  for (int j = 0; j < 44; ++j) acc[j] = 0.f;

  int i = beg + strm;
  int eC = 0, neC = 0;
  if (i < end) { eC = elist[i]; neC = neighbors[eC]; }
  while (i < end) {
    int i2 = i + 8;
    int eN = 0, neN = 0;
    if (i2 < end) { eN = elist[i2]; neN = neighbors[eN]; }

    const unsigned short* rr = rad2 + (size_t)eC * 352;
    const unsigned short* sr = S2v + (size_t)eC * 168;
    const unsigned* fr = unc3 + (size_t)neC * 768;

    float rv0 = bu2f(rr[k]);
    unsigned u1 = *reinterpret_cast<const unsigned*>(rr + 32 + 2 * k);
    uint2 u2v = *reinterpret_cast<const uint2*>(rr + 96 + 4 * k);
    uint2 u3v = *reinterpret_cast<const uint2*>(rr + 224 + 4 * k);

    float s0v = bu2f(sr[0]);
    unsigned su1 = *reinterpret_cast<const unsigned*>(sr + 2 + 2 * q9);
    uint2 su2 = *reinterpret_cast<const uint2*>(sr + 24 + 4 * q9);
    uint2 su3 = *reinterpret_cast<const uint2*>(sr + 64 + 4 * q25);

    unsigned fd0 = fr[k];
    unsigned fu1[5], fu2[5], fu3[13];
#pragma unroll
    for (int j = 0; j < 5; ++j) fu1[j] = fr[32 + j * 32 + k];
#pragma unroll
    for (int j = 0; j < 5; ++j) fu2[j] = fr[192 + j * 32 + k];
#pragma unroll
    for (int j = 0; j < 13; ++j) fu3[j] = fr[352 + j * 32 + k];

    // l0
    acc[0] += rv0 * s0v * lo2f(fd0);

    // l1
    {
      float ra = lo2f(u1), rb_ = hi2f(u1);
      float V[9];
#pragma unroll
      for (int q = 0; q < 9; ++q) {
        unsigned s = (unsigned)__shfl((int)su1, q, 32);
        V[q] = ra * lo2f(s) + rb_ * hi2f(s);
      }
#pragma unroll
      for (int i3 = 0; i3 < 3; ++i3)
#pragma unroll
        for (int j3 = 0; j3 < 3; ++j3) {
          float c = 0.f;
#pragma unroll
          for (int t = 0; t < 3; ++t) {
            int idx = t * 3 + j3;
            float F = (idx & 1) ? hi2f(fu1[idx >> 1]) : lo2f(fu1[idx >> 1]);
            c += V[i3 * 3 + t] * F;
          }
          acc[1 + i3 * 3 + j3] += c;
        }
    }
    // l2
    {
      float ra = lo2f(u2v.x), rb_ = hi2f(u2v.x), rc = lo2f(u2v.y);
      float V[9];
#pragma unroll
      for (int q = 0; q < 9; ++q) {
        unsigned sx = (unsigned)__shfl((int)su2.x, q, 32);
        unsigned sy = (unsigned)__shfl((int)su2.y, q, 32);
        V[q] = ra * lo2f(sx) + rb_ * hi2f(sx) + rc * lo2f(sy);
      }
#pragma unroll
      for (int i3 = 0; i3 < 3; ++i3)
#pragma unroll
        for (int j3 = 0; j3 < 3; ++j3) {
          float c = 0.f;
#pragma unroll
          for (int t = 0; t < 3; ++t) {
            int idx = t * 3 + j3;
            float F = (idx & 1) ? hi2f(fu2[idx >> 1]) : lo2f(fu2[idx >> 1]);
            c += V[i3 * 3 + t] * F;
          }
          acc[10 + i3 * 3 + j3] += c;
        }
    }
    // l3
    {
      float ra = lo2f(u3v.x), rb_ = hi2f(u3v.x), rc = lo2f(u3v.y), rd = hi2f(u3v.y);
      float V[25];
#pragma unroll
      for (int q = 0; q < 25; ++q) {
        unsigned sx = (unsigned)__shfl((int)su3.x, q, 32);
        unsigned sy = (unsigned)__shfl((int)su3.y, q, 32);
        V[q] = ra * lo2f(sx) + rb_ * hi2f(sx) + rc * lo2f(sy) + rd * hi2f(sy);
      }
#pragma unroll
      for (int i5 = 0; i5 < 5; ++i5)
#pragma unroll
        for (int j5 = 0; j5 < 5; ++j5) {
          float c = 0.f;
#pragma unroll
          for (int t = 0; t < 5; ++t) {
            int idx = t * 5 + j5;
            float F = (idx & 1) ? hi2f(fu3[idx >> 1]) : lo2f(fu3[idx >> 1]);
            c += V[i5 * 5 + t] * F;
          }
          acc[19 + i5 * 5 + j5] += c;
        }
    }

    i = i2; eC = eN; neC = neN;
  }
#pragma unroll
  for (int j = 0; j < 44; ++j) acc[j] += __shfl_xor(acc[j], 32);

  __shared__ float buf[4][1408];
  if ((tid & 32) == 0) {
#pragma unroll
    for (int l = 0; l < 4; ++l) {
      int T2 = (cPL[l] + 1) * (cPL[l] + 1);
      for (int q = 0; q < T2; ++q)
        buf[wv][cSOFF[l] + q * 32 + k] = acc[cAOF[l] + q];
    }
  }
  __syncthreads();
  for (int idx = tid; idx < 1408; idx += 256)
    buf[0][idx] = (buf[0][idx] + buf[1][idx]) + (buf[2][idx] + buf[3][idx]);
  __syncthreads();
  unsigned short* crow = ccg + (size_t)a * 960;
  for (int idx = tid; idx < 960; idx += 256) {
    int kk = idx & 31, combo = idx >> 5;
    int l = c_tl[combo], mm = c_tmm[combo], s = c_ts[combo];
    int lp = l + s;
    int Ts = c_pl_r[lp] + 1;
    int Ts2 = Ts * Ts;
    const float* U = ws + c_uof_r[lp];
    const float* pr = &buf[0][c_soff_r[lp]];
    int m = l * l + mm;
    float sacc = 0.f;
    for (int q = 0; q < Ts2; ++q) sacc += U[q * Ts2 + m] * pr[q * 32 + kk];
    crow[idx] = f2bu(sacc);
  }
}

// ---------------- k_out2 (verbatim R7) ----------------
template <int l>
DEV void out_body(const void* __restrict__ ft, const void* __restrict__ wl,
                  const unsigned short* __restrict__ ccg, void* __restrict__ out,
                  int rt, int tid, int isb) {
  constexpr int NMM = 2 * l + 1;
  constexpr int K   = cK[l];
  constexpr int NKS = K / 32;
  constexpr int M   = N_ATOMS * NMM;
  constexpr int NET = (l <= 1) ? 4 : (l == 2 ? 2 : 1);
  int wv = tid >> 6, lane = tid & 63;
  int c0, et0;
  bool active = true;
  if constexpr (l == 0)      { c0 = wv * 32;       et0 = 0; }
  else if constexpr (l == 1) { c0 = wv * 32;       et0 = 0; active = (wv < 3); }
  else if constexpr (l == 2) { c0 = (wv & 1) * 32; et0 = (wv >> 1) * 2; }
  else                       { c0 = 0;             et0 = wv; }
  if (!active) return;
  int ln15 = lane & 15, lhi = lane >> 4;
  int r0 = rt * 64;
  short8 Bf[2][NKS];
#pragma unroll
  for (int ct = 0; ct < 2; ++ct)
#pragma unroll
    for (int ks = 0; ks < NKS; ++ks) {
      int col = c0 + ct * 16 + ln15;
      int kb  = ks * 32 + lhi * 8;
#pragma unroll
      for (int i = 0; i < 8; ++i)
        Bf[ct][ks][i] = ldb(wl, (long)(kb + i) * K + col, isb);
    }
  long abase[NET];
#pragma unroll
  for (int et = 0; et < NET; ++et) {
    int R = r0 + (et0 + et) * 16 + ln15;
    if (R >= M) R = M - 1;
    int a = R / NMM, mm = R - a * NMM;
    abase[et] = (long)a * 960 + cCB[l] + (long)mm * K;
  }
  f32x4 acc[NET][2];
#pragma unroll
  for (int et = 0; et < NET; ++et)
#pragma unroll
    for (int ct = 0; ct < 2; ++ct) acc[et][ct] = (f32x4){0.f, 0.f, 0.f, 0.f};
#pragma unroll
  for (int et = 0; et < NET; ++et) {
#pragma unroll
    for (int ks = 0; ks < NKS; ++ks) {
      short8 Af = *reinterpret_cast<const short8*>(&ccg[abase[et] + ks * 32 + lhi * 8]);
      acc[et][0] = __builtin_amdgcn_mfma_f32_16x16x32_bf16(Af, Bf[0][ks], acc[et][0], 0, 0, 0);
      acc[et][1] = __builtin_amdgcn_mfma_f32_16x16x32_bf16(Af, Bf[1][ks], acc[et][1], 0, 0, 0);
    }
  }
#pragma unroll
  for (int et = 0; et < NET; ++et)
#pragma unroll
    for (int ct = 0; ct < 2; ++ct)
#pragma unroll
      for (int r = 0; r < 4; ++r) {
        int R = r0 + (et0 + et) * 16 + lhi * 4 + r;
        if (R < M) {
          int col = c0 + ct * 16 + ln15;
          long o = (long)R * K + col;
          stf(out, cOUT[l] + o, ldf(ft, o, isb) + acc[et][ct][r], isb);
        }
      }
}

__global__ __launch_bounds__(256) void k_out2(
    const void* __restrict__ f0, const void* __restrict__ f1,
    const void* __restrict__ f2, const void* __restrict__ f3,
    const void* __restrict__ wl0, const void* __restrict__ wl1,
    const void* __restrict__ wl2, const void* __restrict__ wl3,
    const int* __restrict__ flag, const unsigned short* __restrict__ ccg,
    void* __restrict__ out) {
  int isb = *flag;
  int b = blockIdx.x;
  int tid = threadIdx.x;
  if      (b < 40)  out_body<0>(f0, wl0, ccg, out, b,       tid, isb);
  else if (b < 158) out_body<1>(f1, wl1, ccg, out, b - 40,  tid, isb);
  else if (b < 354) out_body<2>(f2, wl2, ccg, out, b - 158, tid, isb);
  else              out_body<3>(f3, wl3, ccg, out, b - 354, tid, isb);
}

// ---------------- launch ----------------
extern "C" void kernel_launch(void* const* d_in, const int* in_sizes, int n_in,
                              void* d_out, int out_size, void* d_ws, size_t ws_size,
                              hipStream_t stream) {
  (void)n_in; (void)out_size; (void)ws_size;
  bool dictord = (in_sizes[1] == 40000);
  const void* rb[4]; const void* sph[4]; const void* ft[4];
  const void *w1[4], *w2[4], *wl[4];
  for (int l = 0; l < 4; ++l) {
    if (dictord) {
      rb[l]  = d_in[3 * l + 0];
      sph[l] = d_in[3 * l + 1];
      ft[l]  = d_in[3 * l + 2];
      w1[l]  = d_in[17 + 3 * l];
      w2[l]  = d_in[18 + 3 * l];
      wl[l]  = d_in[19 + 3 * l];
    } else {
      rb[l]  = d_in[l];
      sph[l] = d_in[4 + l];
      ft[l]  = d_in[8 + l];
      w1[l]  = d_in[17 + l];
      w2[l]  = d_in[21 + l];
      wl[l]  = d_in[25 + l];
    }
  }
  const int* centers   = (const int*)d_in[12];
  const int* neighbors = (const int*)d_in[13];
  const void* u0 = d_in[14];
  const void* u2 = d_in[15];
  const void* u4 = d_in[16];

  float* ws   = (float*)d_ws;
  int*   flag = (int*)(ws + FLAG_OFF);
  unsigned short* rad2 = (unsigned short*)(ws + RAD2_OFF);
  unsigned short* S2v  = (unsigned short*)(ws + S2_OFF);
  unsigned*       unc3 = (unsigned*)(ws + UNC3_OFF);
  unsigned short* ccg  = (unsigned short*)(ws + CCG_OFF);
  int*   cnt   = (int*)(ws + CNT_OFF);
  int*   start = (int*)(ws + START_OFF);
  int*   fill  = (int*)(ws + FILL_OFF);
  int*   elist = (int*)(ws + ELIST_OFF);

  hipMemsetAsync(cnt, 0, N_ATOMS * sizeof(int), stream);
  k_detect<<<1, 64, 0, stream>>>(w2[0], flag);
  k_count<<<(N_EDGES + 255) / 256, 256, 0, stream>>>(centers, cnt);
  k_scan<<<1, 256, 0, stream>>>(cnt, start, fill);
  k_fill<<<(N_EDGES + 255) / 256, 256, 0, stream>>>(centers, fill, elist);
  k_prep<<<208, 256, 0, stream>>>(w1[0], w1[1], w1[2], w1[3],
                                  w2[0], w2[1], w2[2], w2[3],
                                  wl[0], wl[1], wl[2], wl[3],
                                  u0, u2, u4, flag, ws);
  k_sph<<<5000, 256, 0, stream>>>(sph[0], sph[1], sph[2], sph[3], flag, ws, S2v);
  k_radial4<<<2500, 256, 0, stream>>>(rb[0], rb[1], rb[2], rb[3],
                                      w2[0], w2[1], w2[2], w2[3], flag, ws, rad2);
  k_uncfeat<<<N_ATOMS / 2, 64, 0, stream>>>(ft[0], ft[1], ft[2], ft[3], flag, ws, unc3);
  k_edge5<<<N_ATOMS, 256, 0, stream>>>(start, elist, neighbors, ws, rad2, S2v, unc3, ccg);
  k_out2<<<628, 256, 0, stream>>>(ft[0], ft[1], ft[2], ft[3],
                                  wl[0], wl[1], wl[2], wl[3], flag, ccg, (void*)d_out);
}

// Round 11
// 146.970 us; speedup vs baseline: 1.7539x; 1.4112x over previous
//
#include <hip/hip_runtime.h>
#include <hip/hip_bf16.h>

typedef __hip_bfloat16 bf16;
using short8 = __attribute__((ext_vector_type(8))) short;
using f32x4  = __attribute__((ext_vector_type(4))) float;

#define DEV static __device__ __forceinline__

DEV unsigned short f2bu(float f) {
  union { bf16 h; unsigned short u; } v; v.h = __float2bfloat16(f); return v.u;
}
DEV short f2bs(float f) {
  union { bf16 h; short s; } v; v.h = __float2bfloat16(f); return v.s;
}
DEV float bu2f(unsigned short u) {
  union { unsigned x; float f; } v; v.x = ((unsigned)u) << 16; return v.f;
}
DEV float lo2f(unsigned u) { union { unsigned x; float f; } v; v.x = u << 16; return v.f; }
DEV float hi2f(unsigned u) { union { unsigned x; float f; } v; v.x = u & 0xFFFF0000u; return v.f; }
DEV unsigned pk2(float a, float b) { return (unsigned)f2bu(a) | ((unsigned)f2bu(b) << 16); }

// ---- problem constants ----
#define N_ATOMS 2500
#define N_EDGES 40000

constexpr int cK[4]    = {128, 96, 64, 32};
constexpr int cPL[4]   = {0, 2, 2, 4};
constexpr int cLO[4]   = {96, 64, 32, 0};
constexpr int cSOFF[4] = {0, 32, 320, 608};
constexpr int cAOF[4]  = {0, 1, 10, 19};
// ws float-offsets (weights now read directly from inputs; region below RAD2 unused)
constexpr int RAD2_OFF = 53248;                        // [e][352 ushorts]
constexpr int S2_OFF   = RAD2_OFF + N_EDGES * 176;     // [e][168 ushorts]
constexpr int UNC3_OFF = S2_OFF + N_EDGES * 84;        // [a][768 dwords]
constexpr int CCG_OFF  = UNC3_OFF + N_ATOMS * 768;     // [a][960 bf16]
constexpr int CSR_OFF   = CCG_OFF + N_ATOMS * 480;
constexpr int CNT_OFF   = CSR_OFF;
constexpr int START_OFF = CSR_OFF + 2500;
constexpr int FILL_OFF  = CSR_OFF + 5008;
constexpr int ELIST_OFF = CSR_OFF + 7512;

constexpr int cCB[4]  = {0, 128, 416, 736};
constexpr int cOUT[4] = {0, 320000, 1040000, 1840000};

__device__ const int c_tl[30]  = {0,0,0,0, 1,1,1,1,1,1,1,1,1, 2,2,2,2,2,2,2,2,2,2, 3,3,3,3,3,3,3};
__device__ const int c_tmm[30] = {0,0,0,0, 0,0,0,1,1,1,2,2,2, 0,0,1,1,2,2,3,3,4,4, 0,1,2,3,4,5,6};
__device__ const int c_ts[30]  = {0,1,2,3, 0,1,2,0,1,2,0,1,2, 0,1,0,1,0,1,0,1,0,1, 0,0,0,0,0,0,0};
__device__ const int c_soff_r[4] = {0, 32, 320, 608};
__device__ const int c_pl_r[4]   = {0, 2, 2, 4};

// ---------------- k_count ----------------
__global__ __launch_bounds__(256) void k_count(const int* __restrict__ centers, int* __restrict__ cnt) {
  int e = blockIdx.x * 256 + threadIdx.x;
  if (e < N_EDGES) atomicAdd(&cnt[centers[e]], 1);
}

// ---------------- k_scan ----------------
__global__ __launch_bounds__(256) void k_scan(const int* __restrict__ cnt,
                                              int* __restrict__ start, int* __restrict__ fill) {
  __shared__ int part[256];
  int t = threadIdx.x;
  int loc[10];
  int s = 0;
  int base = t * 10;
#pragma unroll
  for (int i = 0; i < 10; ++i) {
    int c = (base + i < N_ATOMS) ? cnt[base + i] : 0;
    loc[i] = s; s += c;
  }
  part[t] = s;
  __syncthreads();
  for (int off = 1; off < 256; off <<= 1) {
    int v = part[t];
    if (t >= off) v += part[t - off];
    __syncthreads();
    part[t] = v;
    __syncthreads();
  }
  int excl = (t == 0) ? 0 : part[t - 1];
#pragma unroll
  for (int i = 0; i < 10; ++i) {
    if (base + i < N_ATOMS) {
      start[base + i] = excl + loc[i];
      fill[base + i]  = excl + loc[i];
    }
  }
  if (t == 255) start[N_ATOMS] = part[255];
}

// ---------------- k_mid pieces ----------------
DEV void sph_body(int e, int q,
                  const float* __restrict__ s0p, const float* __restrict__ s1p,
                  const float* __restrict__ s2p, const float* __restrict__ s3p,
                  const float* __restrict__ u0, const float* __restrict__ u2,
                  const float* __restrict__ u4, unsigned short* __restrict__ S2v) {
  float sp0 = s0p[e];
  float sp1[3], sp2[5], sp3[7];
#pragma unroll
  for (int m = 0; m < 3; ++m) sp1[m] = s1p[(long)e * 3 + m];
#pragma unroll
  for (int m = 0; m < 5; ++m) sp2[m] = s2p[(long)e * 5 + m];
#pragma unroll
  for (int m = 0; m < 7; ++m) sp3[m] = s3p[(long)e * 7 + m];
  unsigned short* out = S2v + (size_t)e * 168;
  if (q < 9) {
    const float* r = u2 + q * 9;
    float s0 = r[0] * sp0;
    float s1 = r[1] * sp1[0] + r[2] * sp1[1] + r[3] * sp1[2];
    float s2 = r[4] * sp2[0] + r[5] * sp2[1] + r[6] * sp2[2] + r[7] * sp2[3] + r[8] * sp2[4];
    *reinterpret_cast<unsigned*>(out + 2 + 2 * q) = pk2(s0, s1);
    *reinterpret_cast<unsigned*>(out + 24 + 4 * q) = pk2(s0, s1);
    out[24 + 4 * q + 2] = f2bu(s2);
    out[24 + 4 * q + 3] = 0;
  }
  if (q < 25) {
    const float* r = u4 + q * 25;
    float w0 = r[0] * sp0;
    float w1 = r[1] * sp1[0] + r[2] * sp1[1] + r[3] * sp1[2];
    float w2 = r[4] * sp2[0] + r[5] * sp2[1] + r[6] * sp2[2] + r[7] * sp2[3] + r[8] * sp2[4];
    float w3 = 0.f;
#pragma unroll
    for (int m = 0; m < 7; ++m) w3 += r[9 + m] * sp3[m];
    *reinterpret_cast<unsigned*>(out + 64 + 4 * q)     = pk2(w0, w1);
    *reinterpret_cast<unsigned*>(out + 64 + 4 * q + 2) = pk2(w2, w3);
  }
  if (q == 31) out[0] = f2bu(u0[0] * sp0);
}

template <int l>
DEV void radial_body(const float* __restrict__ rb, const float* __restrict__ Wr1f,
                     const float* __restrict__ w2, unsigned short* __restrict__ rad2,
                     int e0, int tid, unsigned short (*H)[72]) {
  constexpr int NM = (l == 0) ? 8 : (l == 1) ? 6 : (l == 2) ? 4 : 2;
  constexpr int K  = cK[l];
  {
    int e  = e0 + (tid & 63);
    int j0 = (tid >> 6) * 16;
    float rbv[NM];
#pragma unroll
    for (int n = 0; n < NM; ++n) rbv[n] = rb[(long)e * NM + n];
    float h[16];
#pragma unroll
    for (int j = 0; j < 16; ++j) h[j] = 0.f;
#pragma unroll
    for (int n = 0; n < NM; ++n) {
      float rv = rbv[n];
      const float4* wp = reinterpret_cast<const float4*>(Wr1f + n * 64 + j0);
#pragma unroll
      for (int qq = 0; qq < 4; ++qq) {
        float4 w = wp[qq];
        h[4 * qq + 0] += rv * w.x;
        h[4 * qq + 1] += rv * w.y;
        h[4 * qq + 2] += rv * w.z;
        h[4 * qq + 3] += rv * w.w;
      }
    }
    unsigned short* hrow = H[tid & 63];
#pragma unroll
    for (int j = 0; j < 16; j += 2) {
      float a0 = h[j], a1 = h[j + 1];
      a0 = a0 * (1.0f / (1.0f + __expf(-a0)));
      a1 = a1 * (1.0f / (1.0f + __expf(-a1)));
      *reinterpret_cast<unsigned*>(&hrow[j0 + j]) = pk2(a0, a1);
    }
  }
  __syncthreads();
  int wv = tid >> 6, lane = tid & 63;
  constexpr int NET = (l <= 1) ? 4 : (l == 2 ? 2 : 1);
  int c0, et0;
  bool active = true;
  if constexpr (l == 0)      { c0 = wv * 32;       et0 = 0; }
  else if constexpr (l == 1) { c0 = wv * 32;       et0 = 0; active = (wv < 3); }
  else if constexpr (l == 2) { c0 = (wv & 1) * 32; et0 = (wv >> 1) * 2; }
  else                       { c0 = 0;             et0 = wv; }
  if (!active) return;
  int ln15 = lane & 15, lhi = lane >> 4;
  short8 Bf[2][2];
#pragma unroll
  for (int ct = 0; ct < 2; ++ct)
#pragma unroll
    for (int ks = 0; ks < 2; ++ks) {
      int col = c0 + ct * 16 + ln15;
      int kb  = ks * 32 + lhi * 8;
#pragma unroll
      for (int i = 0; i < 8; ++i)
        Bf[ct][ks][i] = f2bs(w2[(long)(kb + i) * K + col]);
    }
  f32x4 acc[NET][2];
#pragma unroll
  for (int et = 0; et < NET; ++et)
#pragma unroll
    for (int ct = 0; ct < 2; ++ct) acc[et][ct] = (f32x4){0.f, 0.f, 0.f, 0.f};
#pragma unroll
  for (int et = 0; et < NET; ++et) {
#pragma unroll
    for (int ks = 0; ks < 2; ++ks) {
      short8 Af = *reinterpret_cast<const short8*>(&H[(et0 + et) * 16 + ln15][ks * 32 + lhi * 8]);
      acc[et][0] = __builtin_amdgcn_mfma_f32_16x16x32_bf16(Af, Bf[0][ks], acc[et][0], 0, 0, 0);
      acc[et][1] = __builtin_amdgcn_mfma_f32_16x16x32_bf16(Af, Bf[1][ks], acc[et][1], 0, 0, 0);
    }
  }
#pragma unroll
  for (int ct = 0; ct < 2; ++ct) {
    int c = c0 + ct * 16 + ln15;
    int lsec = 3 - (c >> 5);
    int kk = c & 31;
    int sec  = (lsec == 0) ? 0 : (lsec == 1) ? 32 : (lsec == 2) ? 96 : 224;
    int slot = (lsec >= 2) ? 4 : ((lsec == 1) ? 2 : 1);
    int off = sec + slot * kk + l;
#pragma unroll
    for (int et = 0; et < NET; ++et)
#pragma unroll
      for (int r = 0; r < 4; ++r) {
        int erow = (et0 + et) * 16 + lhi * 4 + r;
        rad2[(size_t)(e0 + erow) * 352 + off] = f2bu(acc[et][ct][r]);
      }
  }
}

template <int l>
DEV void unc_one(int a, int k,
                 const float* __restrict__ f0, const float* __restrict__ f1,
                 const float* __restrict__ f2, const float* __restrict__ f3,
                 const float* __restrict__ U, unsigned* __restrict__ dst) {
  constexpr int T2 = (cPL[l] + 1) * (cPL[l] + 1);
  constexpr int M = (l + 1) * (l + 1);
  constexpr int NB = (T2 + 1) / 2;
  constexpr int base = (l == 0) ? 0 : (l == 1) ? 32 : (l == 2) ? 192 : 352;
  const float* fps[4] = {f0, f1, f2, f3};
  float fc[M];
#pragma unroll
  for (int lp = 0; lp <= l; ++lp) {
    const float* fp = fps[lp];
#pragma unroll
    for (int mm = 0; mm < 2 * lp + 1; ++mm)
      fc[lp * lp + mm] = fp[((long)a * (2 * lp + 1) + mm) * cK[lp] + cLO[l] + k];
  }
  float v[T2];
#pragma unroll
  for (int q = 0; q < T2; ++q) {
    float s = 0.f;
#pragma unroll
    for (int m = 0; m < M; ++m) s += U[q * T2 + m] * fc[m];
    v[q] = s;
  }
#pragma unroll
  for (int q2 = 0; q2 < NB; ++q2) {
    float a0 = v[2 * q2];
    float a1 = (2 * q2 + 1 < T2) ? v[2 * q2 + 1] : 0.f;
    dst[base + q2 * 32 + k] = pk2(a0, a1);
  }
}

// fill(157) | sph(5000) | radial(2500) | uncfeat(313)
__global__ __launch_bounds__(256) void k_mid(
    const float* __restrict__ rb0, const float* __restrict__ rb1,
    const float* __restrict__ rb2, const float* __restrict__ rb3,
    const float* __restrict__ s0p, const float* __restrict__ s1p,
    const float* __restrict__ s2p, const float* __restrict__ s3p,
    const float* __restrict__ f0, const float* __restrict__ f1,
    const float* __restrict__ f2, const float* __restrict__ f3,
    const float* __restrict__ w10, const float* __restrict__ w11,
    const float* __restrict__ w12, const float* __restrict__ w13,
    const float* __restrict__ w20, const float* __restrict__ w21,
    const float* __restrict__ w22, const float* __restrict__ w23,
    const float* __restrict__ u0, const float* __restrict__ u2,
    const float* __restrict__ u4,
    const int* __restrict__ centers, int* __restrict__ fill, int* __restrict__ elist,
    unsigned short* __restrict__ rad2, unsigned short* __restrict__ S2v,
    unsigned* __restrict__ unc3) {
  __shared__ __align__(16) unsigned short H[64][72];
  int b = blockIdx.x;
  int tid = threadIdx.x;
  if (b < 157) {
    int e = b * 256 + tid;
    if (e < N_EDGES) {
      int pos = atomicAdd(&fill[centers[e]], 1);
      elist[pos] = e;
    }
  } else if (b < 5157) {
    int e = (b - 157) * 8 + (tid >> 5);
    sph_body(e, tid & 31, s0p, s1p, s2p, s3p, u0, u2, u4, S2v);
  } else if (b < 7657) {
    int rbk = b - 5157;
    int l = rbk / 625;
    int e0 = (rbk - l * 625) * 64;
    switch (l) {
      case 0: radial_body<0>(rb0, w10, w20, rad2, e0, tid, H); break;
      case 1: radial_body<1>(rb1, w11, w21, rad2, e0, tid, H); break;
      case 2: radial_body<2>(rb2, w12, w22, rad2, e0, tid, H); break;
      default: radial_body<3>(rb3, w13, w23, rad2, e0, tid, H); break;
    }
  } else {
    int a = (b - 7657) * 8 + (tid >> 5);
    if (a >= N_ATOMS) return;
    int k = tid & 31;
    unsigned* dst = unc3 + (size_t)a * 768;
    unc_one<0>(a, k, f0, f1, f2, f3, u0, dst);
    unc_one<1>(a, k, f0, f1, f2, f3, u2, dst);
    unc_one<2>(a, k, f0, f1, f2, f3, u2, dst);
    unc_one<3>(a, k, f0, f1, f2, f3, u4, dst);
  }
}

// ---------------- k_edge5: packed loads + packed shfl + prefetch ----------------
__global__ __launch_bounds__(256) void k_edge5(
    const int* __restrict__ start, const int* __restrict__ elist,
    const int* __restrict__ neighbors,
    const float* __restrict__ u0, const float* __restrict__ u2,
    const float* __restrict__ u4,
    const unsigned short* __restrict__ rad2, const unsigned short* __restrict__ S2v,
    const unsigned* __restrict__ unc3, unsigned short* __restrict__ ccg) {
  int a = blockIdx.x;
  int tid = threadIdx.x;
  int wv = tid >> 6;
  int k = tid & 31;
  int strm = tid >> 5;
  int beg = start[a], end = start[a + 1];
  int q9  = (k < 9)  ? k : 8;
  int q25 = (k < 25) ? k : 24;

  float acc[44];
#pragma unroll
  for (int j = 0; j < 44; ++j) acc[j] = 0.f;

  int i = beg + strm;
  int eC = 0, neC = 0;
  if (i < end) { eC = elist[i]; neC = neighbors[eC]; }
  while (i < end) {
    int i2 = i + 8;
    int eN = 0, neN = 0;
    if (i2 < end) { eN = elist[i2]; neN = neighbors[eN]; }

    const unsigned short* rr = rad2 + (size_t)eC * 352;
    const unsigned short* sr = S2v + (size_t)eC * 168;
    const unsigned* fr = unc3 + (size_t)neC * 768;

    float rv0 = bu2f(rr[k]);
    unsigned u1 = *reinterpret_cast<const unsigned*>(rr + 32 + 2 * k);
    uint2 u2v = *reinterpret_cast<const uint2*>(rr + 96 + 4 * k);
    uint2 u3v = *reinterpret_cast<const uint2*>(rr + 224 + 4 * k);

    float s0v = bu2f(sr[0]);
    unsigned su1 = *reinterpret_cast<const unsigned*>(sr + 2 + 2 * q9);
    uint2 su2 = *reinterpret_cast<const uint2*>(sr + 24 + 4 * q9);
    uint2 su3 = *reinterpret_cast<const uint2*>(sr + 64 + 4 * q25);

    unsigned fd0 = fr[k];
    unsigned fu1[5], fu2[5], fu3[13];
#pragma unroll
    for (int j = 0; j < 5; ++j) fu1[j] = fr[32 + j * 32 + k];
#pragma unroll
    for (int j = 0; j < 5; ++j) fu2[j] = fr[192 + j * 32 + k];
#pragma unroll
    for (int j = 0; j < 13; ++j) fu3[j] = fr[352 + j * 32 + k];

    // l0
    acc[0] += rv0 * s0v * lo2f(fd0);

    // l1
    {
      float ra = lo2f(u1), rb_ = hi2f(u1);
      float V[9];
#pragma unroll
      for (int q = 0; q < 9; ++q) {
        unsigned s = (unsigned)__shfl((int)su1, q, 32);
        V[q] = ra * lo2f(s) + rb_ * hi2f(s);
      }
#pragma unroll
      for (int i3 = 0; i3 < 3; ++i3)
#pragma unroll
        for (int j3 = 0; j3 < 3; ++j3) {
          float c = 0.f;
#pragma unroll
          for (int t = 0; t < 3; ++t) {
            int idx = t * 3 + j3;
            float F = (idx & 1) ? hi2f(fu1[idx >> 1]) : lo2f(fu1[idx >> 1]);
            c += V[i3 * 3 + t] * F;
          }
          acc[1 + i3 * 3 + j3] += c;
        }
    }
    // l2
    {
      float ra = lo2f(u2v.x), rb_ = hi2f(u2v.x), rc = lo2f(u2v.y);
      float V[9];
#pragma unroll
      for (int q = 0; q < 9; ++q) {
        unsigned sx = (unsigned)__shfl((int)su2.x, q, 32);
        unsigned sy = (unsigned)__shfl((int)su2.y, q, 32);
        V[q] = ra * lo2f(sx) + rb_ * hi2f(sx) + rc * lo2f(sy);
      }
#pragma unroll
      for (int i3 = 0; i3 < 3; ++i3)
#pragma unroll
        for (int j3 = 0; j3 < 3; ++j3) {
          float c = 0.f;
#pragma unroll
          for (int t = 0; t < 3; ++t) {
            int idx = t * 3 + j3;
            float F = (idx & 1) ? hi2f(fu2[idx >> 1]) : lo2f(fu2[idx >> 1]);
            c += V[i3 * 3 + t] * F;
          }
          acc[10 + i3 * 3 + j3] += c;
        }
    }
    // l3
    {
      float ra = lo2f(u3v.x), rb_ = hi2f(u3v.x), rc = lo2f(u3v.y), rd = hi2f(u3v.y);
      float V[25];
#pragma unroll
      for (int q = 0; q < 25; ++q) {
        unsigned sx = (unsigned)__shfl((int)su3.x, q, 32);
        unsigned sy = (unsigned)__shfl((int)su3.y, q, 32);
        V[q] = ra * lo2f(sx) + rb_ * hi2f(sx) + rc * lo2f(sy) + rd * hi2f(sy);
      }
#pragma unroll
      for (int i5 = 0; i5 < 5; ++i5)
#pragma unroll
        for (int j5 = 0; j5 < 5; ++j5) {
          float c = 0.f;
#pragma unroll
          for (int t = 0; t < 5; ++t) {
            int idx = t * 5 + j5;
            float F = (idx & 1) ? hi2f(fu3[idx >> 1]) : lo2f(fu3[idx >> 1]);
            c += V[i5 * 5 + t] * F;
          }
          acc[19 + i5 * 5 + j5] += c;
        }
    }

    i = i2; eC = eN; neC = neN;
  }
#pragma unroll
  for (int j = 0; j < 44; ++j) acc[j] += __shfl_xor(acc[j], 32);

  __shared__ float buf[4][1408];
  if ((tid & 32) == 0) {
#pragma unroll
    for (int l = 0; l < 4; ++l) {
      int T2 = (cPL[l] + 1) * (cPL[l] + 1);
      for (int q = 0; q < T2; ++q)
        buf[wv][cSOFF[l] + q * 32 + k] = acc[cAOF[l] + q];
    }
  }
  __syncthreads();
  for (int idx = tid; idx < 1408; idx += 256)
    buf[0][idx] = (buf[0][idx] + buf[1][idx]) + (buf[2][idx] + buf[3][idx]);
  __syncthreads();
  unsigned short* crow = ccg + (size_t)a * 960;
  for (int idx = tid; idx < 960; idx += 256) {
    int kk = idx & 31, combo = idx >> 5;
    int l = c_tl[combo], mm = c_tmm[combo], s = c_ts[combo];
    int lp = l + s;
    int Ts = c_pl_r[lp] + 1;
    int Ts2 = Ts * Ts;
    const float* U = (lp == 0) ? u0 : ((lp == 3) ? u4 : u2);
    const float* pr = &buf[0][c_soff_r[lp]];
    int m = l * l + mm;
    float sacc = 0.f;
    for (int q = 0; q < Ts2; ++q) sacc += U[q * Ts2 + m] * pr[q * 32 + kk];
    crow[idx] = f2bu(sacc);
  }
}

// ---------------- k_out2: MFMA GEMM  out = feats + concat @ Wl ----------------
template <int l>
DEV void out_body(const float* __restrict__ ft, const float* __restrict__ wl,
                  const unsigned short* __restrict__ ccg, float* __restrict__ out,
                  int rt, int tid) {
  constexpr int NMM = 2 * l + 1;
  constexpr int K   = cK[l];
  constexpr int NKS = K / 32;
  constexpr int M   = N_ATOMS * NMM;
  constexpr int NET = (l <= 1) ? 4 : (l == 2 ? 2 : 1);
  int wv = tid >> 6, lane = tid & 63;
  int c0, et0;
  bool active = true;
  if constexpr (l == 0)      { c0 = wv * 32;       et0 = 0; }
  else if constexpr (l == 1) { c0 = wv * 32;       et0 = 0; active = (wv < 3); }
  else if constexpr (l == 2) { c0 = (wv & 1) * 32; et0 = (wv >> 1) * 2; }
  else                       { c0 = 0;             et0 = wv; }
  if (!active) return;
  int ln15 = lane & 15, lhi = lane >> 4;
  int r0 = rt * 64;
  short8 Bf[2][NKS];
#pragma unroll
  for (int ct = 0; ct < 2; ++ct)
#pragma unroll
    for (int ks = 0; ks < NKS; ++ks) {
      int col = c0 + ct * 16 + ln15;
      int kb  = ks * 32 + lhi * 8;
#pragma unroll
      for (int i = 0; i < 8; ++i)
        Bf[ct][ks][i] = f2bs(wl[(long)(kb + i) * K + col]);
    }
  long abase[NET];
#pragma unroll
  for (int et = 0; et < NET; ++et) {
    int R = r0 + (et0 + et) * 16 + ln15;
    if (R >= M) R = M - 1;
    int a = R / NMM, mm = R - a * NMM;
    abase[et] = (long)a * 960 + cCB[l] + (long)mm * K;
  }
  f32x4 acc[NET][2];
#pragma unroll
  for (int et = 0; et < NET; ++et)
#pragma unroll
    for (int ct = 0; ct < 2; ++ct) acc[et][ct] = (f32x4){0.f, 0.f, 0.f, 0.f};
#pragma unroll
  for (int et = 0; et < NET; ++et) {
#pragma unroll
    for (int ks = 0; ks < NKS; ++ks) {
      short8 Af = *reinterpret_cast<const short8*>(&ccg[abase[et] + ks * 32 + lhi * 8]);
      acc[et][0] = __builtin_amdgcn_mfma_f32_16x16x32_bf16(Af, Bf[0][ks], acc[et][0], 0, 0, 0);
      acc[et][1] = __builtin_amdgcn_mfma_f32_16x16x32_bf16(Af, Bf[1][ks], acc[et][1], 0, 0, 0);
    }
  }
#pragma unroll
  for (int et = 0; et < NET; ++et)
#pragma unroll
    for (int ct = 0; ct < 2; ++ct)
#pragma unroll
      for (int r = 0; r < 4; ++r) {
        int R = r0 + (et0 + et) * 16 + lhi * 4 + r;
        if (R < M) {
          int col = c0 + ct * 16 + ln15;
          long o = (long)R * K + col;
          out[cOUT[l] + o] = ft[o] + acc[et][ct][r];
        }
      }
}

__global__ __launch_bounds__(256) void k_out2(
    const float* __restrict__ f0, const float* __restrict__ f1,
    const float* __restrict__ f2, const float* __restrict__ f3,
    const float* __restrict__ wl0, const float* __restrict__ wl1,
    const float* __restrict__ wl2, const float* __restrict__ wl3,
    const unsigned short* __restrict__ ccg, float* __restrict__ out) {
  int b = blockIdx.x;
  int tid = threadIdx.x;
  if      (b < 40)  out_body<0>(f0, wl0, ccg, out, b,       tid);
  else if (b < 158) out_body<1>(f1, wl1, ccg, out, b - 40,  tid);
  else if (b < 354) out_body<2>(f2, wl2, ccg, out, b - 158, tid);
  else              out_body<3>(f3, wl3, ccg, out, b - 354, tid);
}

// ---------------- launch ----------------
extern "C" void kernel_launch(void* const* d_in, const int* in_sizes, int n_in,
                              void* d_out, int out_size, void* d_ws, size_t ws_size,
                              hipStream_t stream) {
  (void)n_in; (void)out_size; (void)ws_size;
  bool dictord = (in_sizes[1] == 40000);
  const float* rb[4]; const float* sph[4]; const float* ft[4];
  const float *w1[4], *w2[4], *wl[4];
  for (int l = 0; l < 4; ++l) {
    if (dictord) {
      rb[l]  = (const float*)d_in[3 * l + 0];
      sph[l] = (const float*)d_in[3 * l + 1];
      ft[l]  = (const float*)d_in[3 * l + 2];
      w1[l]  = (const float*)d_in[17 + 3 * l];
      w2[l]  = (const float*)d_in[18 + 3 * l];
      wl[l]  = (const float*)d_in[19 + 3 * l];
    } else {
      rb[l]  = (const float*)d_in[l];
      sph[l] = (const float*)d_in[4 + l];
      ft[l]  = (const float*)d_in[8 + l];
      w1[l]  = (const float*)d_in[17 + l];
      w2[l]  = (const float*)d_in[21 + l];
      wl[l]  = (const float*)d_in[25 + l];
    }
  }
  const int* centers   = (const int*)d_in[12];
  const int* neighbors = (const int*)d_in[13];
  const float* u0 = (const float*)d_in[14];
  const float* u2 = (const float*)d_in[15];
  const float* u4 = (const float*)d_in[16];

  float* ws = (float*)d_ws;
  unsigned short* rad2 = (unsigned short*)(ws + RAD2_OFF);
  unsigned short* S2v  = (unsigned short*)(ws + S2_OFF);
  unsigned*       unc3 = (unsigned*)(ws + UNC3_OFF);
  unsigned short* ccg  = (unsigned short*)(ws + CCG_OFF);
  int* cnt   = (int*)(ws + CNT_OFF);
  int* start = (int*)(ws + START_OFF);
  int* fill  = (int*)(ws + FILL_OFF);
  int* elist = (int*)(ws + ELIST_OFF);

  hipMemsetAsync(cnt, 0, N_ATOMS * sizeof(int), stream);
  k_count<<<157, 256, 0, stream>>>(centers, cnt);
  k_scan<<<1, 256, 0, stream>>>(cnt, start, fill);
  k_mid<<<7970, 256, 0, stream>>>(rb[0], rb[1], rb[2], rb[3],
                                  sph[0], sph[1], sph[2], sph[3],
                                  ft[0], ft[1], ft[2], ft[3],
                                  w1[0], w1[1], w1[2], w1[3],
                                  w2[0], w2[1], w2[2], w2[3],
                                  u0, u2, u4,
                                  centers, fill, elist, rad2, S2v, unc3);
  k_edge5<<<N_ATOMS, 256, 0, stream>>>(start, elist, neighbors, u0, u2, u4,
                                       rad2, S2v, unc3, ccg);
  k_out2<<<628, 256, 0, stream>>>(ft[0], ft[1], ft[2], ft[3],
                                  wl[0], wl[1], wl[2], wl[3], ccg, (float*)d_out);
}

// Round 12
// 145.200 us; speedup vs baseline: 1.7753x; 1.0122x over previous
//
#include <hip/hip_runtime.h>
#include <hip/hip_bf16.h>

typedef __hip_bfloat16 bf16;
using short8 = __attribute__((ext_vector_type(8))) short;
using f32x4  = __attribute__((ext_vector_type(4))) float;

#define DEV static __device__ __forceinline__

DEV unsigned short f2bu(float f) {
  union { bf16 h; unsigned short u; } v; v.h = __float2bfloat16(f); return v.u;
}
DEV short f2bs(float f) {
  union { bf16 h; short s; } v; v.h = __float2bfloat16(f); return v.s;
}
DEV float bu2f(unsigned short u) {
  union { unsigned x; float f; } v; v.x = ((unsigned)u) << 16; return v.f;
}
DEV float lo2f(unsigned u) { union { unsigned x; float f; } v; v.x = u << 16; return v.f; }
DEV float hi2f(unsigned u) { union { unsigned x; float f; } v; v.x = u & 0xFFFF0000u; return v.f; }
DEV unsigned pk2(float a, float b) { return (unsigned)f2bu(a) | ((unsigned)f2bu(b) << 16); }

// ---- problem constants ----
#define N_ATOMS 2500
#define N_EDGES 40000

constexpr int cK[4]    = {128, 96, 64, 32};
constexpr int cPL[4]   = {0, 2, 2, 4};
constexpr int cLO[4]   = {96, 64, 32, 0};
constexpr int cSOFF[4] = {0, 32, 320, 608};
constexpr int cAOF[4]  = {0, 1, 10, 19};
// ws float-offsets
constexpr int RAD2_OFF = 53248;                        // [pos][352 ushorts] (elist order)
constexpr int S2_OFF   = RAD2_OFF + N_EDGES * 176;     // [pos][168 ushorts] (elist order)
constexpr int UNC3_OFF = S2_OFF + N_EDGES * 84;        // [a][768 dwords]
constexpr int CCG_OFF  = UNC3_OFF + N_ATOMS * 768;     // [a][960 bf16]
constexpr int CSR_OFF   = CCG_OFF + N_ATOMS * 480;
constexpr int CNT_OFF   = CSR_OFF;
constexpr int START_OFF = CSR_OFF + 2500;
constexpr int FILL_OFF  = CSR_OFF + 5008;
constexpr int ELIST_OFF = CSR_OFF + 7512;              // unused now (kept for layout stability)
constexpr int INV_OFF   = CSR_OFF + 47512;             // [e] -> pos
constexpr int NLIST_OFF = CSR_OFF + 87512;             // [pos] -> neighbor atom

constexpr int cCB[4]  = {0, 128, 416, 736};
constexpr int cOUT[4] = {0, 320000, 1040000, 1840000};

__device__ const int c_tl[30]  = {0,0,0,0, 1,1,1,1,1,1,1,1,1, 2,2,2,2,2,2,2,2,2,2, 3,3,3,3,3,3,3};
__device__ const int c_tmm[30] = {0,0,0,0, 0,0,0,1,1,1,2,2,2, 0,0,1,1,2,2,3,3,4,4, 0,1,2,3,4,5,6};
__device__ const int c_ts[30]  = {0,1,2,3, 0,1,2,0,1,2,0,1,2, 0,1,0,1,0,1,0,1,0,1, 0,0,0,0,0,0,0};
__device__ const int c_soff_r[4] = {0, 32, 320, 608};
__device__ const int c_pl_r[4]   = {0, 2, 2, 4};
// U section base in the LDS-staged U (Ush): lp=0 -> 0, lp=1/2 -> 1, lp=3 -> 82
__device__ const int c_ubase[4] = {0, 1, 1, 82};

// ---------------- k_count ----------------
__global__ __launch_bounds__(256) void k_count(const int* __restrict__ centers, int* __restrict__ cnt) {
  int e = blockIdx.x * 256 + threadIdx.x;
  if (e < N_EDGES) atomicAdd(&cnt[centers[e]], 1);
}

// ---------------- k_scan ----------------
__global__ __launch_bounds__(256) void k_scan(const int* __restrict__ cnt,
                                              int* __restrict__ start, int* __restrict__ fill) {
  __shared__ int part[256];
  int t = threadIdx.x;
  int loc[10];
  int s = 0;
  int base = t * 10;
#pragma unroll
  for (int i = 0; i < 10; ++i) {
    int c = (base + i < N_ATOMS) ? cnt[base + i] : 0;
    loc[i] = s; s += c;
  }
  part[t] = s;
  __syncthreads();
  for (int off = 1; off < 256; off <<= 1) {
    int v = part[t];
    if (t >= off) v += part[t - off];
    __syncthreads();
    part[t] = v;
    __syncthreads();
  }
  int excl = (t == 0) ? 0 : part[t - 1];
#pragma unroll
  for (int i = 0; i < 10; ++i) {
    if (base + i < N_ATOMS) {
      start[base + i] = excl + loc[i];
      fill[base + i]  = excl + loc[i];
    }
  }
  if (t == 255) start[N_ATOMS] = part[255];
}

// ---------------- k_fill: elist-order mapping + neighbor list ----------------
__global__ __launch_bounds__(256) void k_fill(const int* __restrict__ centers,
                                              const int* __restrict__ neighbors,
                                              int* __restrict__ fill,
                                              int* __restrict__ inv, int* __restrict__ nlist) {
  int e = blockIdx.x * 256 + threadIdx.x;
  if (e >= N_EDGES) return;
  int pos = atomicAdd(&fill[centers[e]], 1);
  inv[e] = pos;
  nlist[pos] = neighbors[e];
}

// ---------------- k_mid pieces ----------------
DEV void sph_body(int e, int q,
                  const float* __restrict__ s0p, const float* __restrict__ s1p,
                  const float* __restrict__ s2p, const float* __restrict__ s3p,
                  const float* __restrict__ u0, const float* __restrict__ u2,
                  const float* __restrict__ u4, const int* __restrict__ inv,
                  unsigned short* __restrict__ S2v) {
  float sp0 = s0p[e];
  float sp1[3], sp2[5], sp3[7];
#pragma unroll
  for (int m = 0; m < 3; ++m) sp1[m] = s1p[(long)e * 3 + m];
#pragma unroll
  for (int m = 0; m < 5; ++m) sp2[m] = s2p[(long)e * 5 + m];
#pragma unroll
  for (int m = 0; m < 7; ++m) sp3[m] = s3p[(long)e * 7 + m];
  unsigned short* out = S2v + (size_t)inv[e] * 168;
  if (q < 9) {
    const float* r = u2 + q * 9;
    float s0 = r[0] * sp0;
    float s1 = r[1] * sp1[0] + r[2] * sp1[1] + r[3] * sp1[2];
    float s2 = r[4] * sp2[0] + r[5] * sp2[1] + r[6] * sp2[2] + r[7] * sp2[3] + r[8] * sp2[4];
    *reinterpret_cast<unsigned*>(out + 2 + 2 * q) = pk2(s0, s1);
    *reinterpret_cast<unsigned*>(out + 24 + 4 * q) = pk2(s0, s1);
    out[24 + 4 * q + 2] = f2bu(s2);
    out[24 + 4 * q + 3] = 0;
  }
  if (q < 25) {
    const float* r = u4 + q * 25;
    float w0 = r[0] * sp0;
    float w1 = r[1] * sp1[0] + r[2] * sp1[1] + r[3] * sp1[2];
    float w2 = r[4] * sp2[0] + r[5] * sp2[1] + r[6] * sp2[2] + r[7] * sp2[3] + r[8] * sp2[4];
    float w3 = 0.f;
#pragma unroll
    for (int m = 0; m < 7; ++m) w3 += r[9 + m] * sp3[m];
    *reinterpret_cast<unsigned*>(out + 64 + 4 * q)     = pk2(w0, w1);
    *reinterpret_cast<unsigned*>(out + 64 + 4 * q + 2) = pk2(w2, w3);
  }
  if (q == 31) out[0] = f2bu(u0[0] * sp0);
}

template <int l>
DEV void radial_body(const float* __restrict__ rb, const float* __restrict__ Wr1f,
                     const float* __restrict__ w2, const int* __restrict__ inv,
                     unsigned short* __restrict__ rad2,
                     int e0, int tid, unsigned short (*H)[72]) {
  constexpr int NM = (l == 0) ? 8 : (l == 1) ? 6 : (l == 2) ? 4 : 2;
  constexpr int K  = cK[l];
  {
    int e  = e0 + (tid & 63);
    int j0 = (tid >> 6) * 16;
    float rbv[NM];
#pragma unroll
    for (int n = 0; n < NM; ++n) rbv[n] = rb[(long)e * NM + n];
    float h[16];
#pragma unroll
    for (int j = 0; j < 16; ++j) h[j] = 0.f;
#pragma unroll
    for (int n = 0; n < NM; ++n) {
      float rv = rbv[n];
      const float4* wp = reinterpret_cast<const float4*>(Wr1f + n * 64 + j0);
#pragma unroll
      for (int qq = 0; qq < 4; ++qq) {
        float4 w = wp[qq];
        h[4 * qq + 0] += rv * w.x;
        h[4 * qq + 1] += rv * w.y;
        h[4 * qq + 2] += rv * w.z;
        h[4 * qq + 3] += rv * w.w;
      }
    }
    unsigned short* hrow = H[tid & 63];
#pragma unroll
    for (int j = 0; j < 16; j += 2) {
      float a0 = h[j], a1 = h[j + 1];
      a0 = a0 * (1.0f / (1.0f + __expf(-a0)));
      a1 = a1 * (1.0f / (1.0f + __expf(-a1)));
      *reinterpret_cast<unsigned*>(&hrow[j0 + j]) = pk2(a0, a1);
    }
  }
  __syncthreads();
  int wv = tid >> 6, lane = tid & 63;
  constexpr int NET = (l <= 1) ? 4 : (l == 2 ? 2 : 1);
  int c0, et0;
  bool active = true;
  if constexpr (l == 0)      { c0 = wv * 32;       et0 = 0; }
  else if constexpr (l == 1) { c0 = wv * 32;       et0 = 0; active = (wv < 3); }
  else if constexpr (l == 2) { c0 = (wv & 1) * 32; et0 = (wv >> 1) * 2; }
  else                       { c0 = 0;             et0 = wv; }
  if (!active) return;
  int ln15 = lane & 15, lhi = lane >> 4;
  short8 Bf[2][2];
#pragma unroll
  for (int ct = 0; ct < 2; ++ct)
#pragma unroll
    for (int ks = 0; ks < 2; ++ks) {
      int col = c0 + ct * 16 + ln15;
      int kb  = ks * 32 + lhi * 8;
#pragma unroll
      for (int i = 0; i < 8; ++i)
        Bf[ct][ks][i] = f2bs(w2[(long)(kb + i) * K + col]);
    }
  // destination rows (elist positions) for this thread's output rows
  int rowp[NET][4];
#pragma unroll
  for (int et = 0; et < NET; ++et)
#pragma unroll
    for (int r = 0; r < 4; ++r)
      rowp[et][r] = inv[e0 + (et0 + et) * 16 + lhi * 4 + r];
  f32x4 acc[NET][2];
#pragma unroll
  for (int et = 0; et < NET; ++et)
#pragma unroll
    for (int ct = 0; ct < 2; ++ct) acc[et][ct] = (f32x4){0.f, 0.f, 0.f, 0.f};
#pragma unroll
  for (int et = 0; et < NET; ++et) {
#pragma unroll
    for (int ks = 0; ks < 2; ++ks) {
      short8 Af = *reinterpret_cast<const short8*>(&H[(et0 + et) * 16 + ln15][ks * 32 + lhi * 8]);
      acc[et][0] = __builtin_amdgcn_mfma_f32_16x16x32_bf16(Af, Bf[0][ks], acc[et][0], 0, 0, 0);
      acc[et][1] = __builtin_amdgcn_mfma_f32_16x16x32_bf16(Af, Bf[1][ks], acc[et][1], 0, 0, 0);
    }
  }
#pragma unroll
  for (int ct = 0; ct < 2; ++ct) {
    int c = c0 + ct * 16 + ln15;
    int lsec = 3 - (c >> 5);
    int kk = c & 31;
    int sec  = (lsec == 0) ? 0 : (lsec == 1) ? 32 : (lsec == 2) ? 96 : 224;
    int slot = (lsec >= 2) ? 4 : ((lsec == 1) ? 2 : 1);
    int off = sec + slot * kk + l;
#pragma unroll
    for (int et = 0; et < NET; ++et)
#pragma unroll
      for (int r = 0; r < 4; ++r)
        rad2[(size_t)rowp[et][r] * 352 + off] = f2bu(acc[et][ct][r]);
  }
}

template <int l>
DEV void unc_one(int a, int k,
                 const float* __restrict__ f0, const float* __restrict__ f1,
                 const float* __restrict__ f2, const float* __restrict__ f3,
                 const float* __restrict__ U, unsigned* __restrict__ dst) {
  constexpr int T2 = (cPL[l] + 1) * (cPL[l] + 1);
  constexpr int M = (l + 1) * (l + 1);
  constexpr int NB = (T2 + 1) / 2;
  constexpr int base = (l == 0) ? 0 : (l == 1) ? 32 : (l == 2) ? 192 : 352;
  const float* fps[4] = {f0, f1, f2, f3};
  float fc[M];
#pragma unroll
  for (int lp = 0; lp <= l; ++lp) {
    const float* fp = fps[lp];
#pragma unroll
    for (int mm = 0; mm < 2 * lp + 1; ++mm)
      fc[lp * lp + mm] = fp[((long)a * (2 * lp + 1) + mm) * cK[lp] + cLO[l] + k];
  }
  float v[T2];
#pragma unroll
  for (int q = 0; q < T2; ++q) {
    float s = 0.f;
#pragma unroll
    for (int m = 0; m < M; ++m) s += U[q * T2 + m] * fc[m];
    v[q] = s;
  }
#pragma unroll
  for (int q2 = 0; q2 < NB; ++q2) {
    float a0 = v[2 * q2];
    float a1 = (2 * q2 + 1 < T2) ? v[2 * q2 + 1] : 0.f;
    dst[base + q2 * 32 + k] = pk2(a0, a1);
  }
}

// sph(5000) | radial(2500) | uncfeat(313)
__global__ __launch_bounds__(256) void k_mid(
    const float* __restrict__ rb0, const float* __restrict__ rb1,
    const float* __restrict__ rb2, const float* __restrict__ rb3,
    const float* __restrict__ s0p, const float* __restrict__ s1p,
    const float* __restrict__ s2p, const float* __restrict__ s3p,
    const float* __restrict__ f0, const float* __restrict__ f1,
    const float* __restrict__ f2, const float* __restrict__ f3,
    const float* __restrict__ w10, const float* __restrict__ w11,
    const float* __restrict__ w12, const float* __restrict__ w13,
    const float* __restrict__ w20, const float* __restrict__ w21,
    const float* __restrict__ w22, const float* __restrict__ w23,
    const float* __restrict__ u0, const float* __restrict__ u2,
    const float* __restrict__ u4, const int* __restrict__ inv,
    unsigned short* __restrict__ rad2, unsigned short* __restrict__ S2v,
    unsigned* __restrict__ unc3) {
  __shared__ __align__(16) unsigned short H[64][72];
  int b = blockIdx.x;
  int tid = threadIdx.x;
  if (b < 5000) {
    int e = b * 8 + (tid >> 5);
    sph_body(e, tid & 31, s0p, s1p, s2p, s3p, u0, u2, u4, inv, S2v);
  } else if (b < 7500) {
    int rbk = b - 5000;
    int l = rbk / 625;
    int e0 = (rbk - l * 625) * 64;
    switch (l) {
      case 0: radial_body<0>(rb0, w10, w20, inv, rad2, e0, tid, H); break;
      case 1: radial_body<1>(rb1, w11, w21, inv, rad2, e0, tid, H); break;
      case 2: radial_body<2>(rb2, w12, w22, inv, rad2, e0, tid, H); break;
      default: radial_body<3>(rb3, w13, w23, inv, rad2, e0, tid, H); break;
    }
  } else {
    int a = (b - 7500) * 8 + (tid >> 5);
    if (a >= N_ATOMS) return;
    int k = tid & 31;
    unsigned* dst = unc3 + (size_t)a * 768;
    unc_one<0>(a, k, f0, f1, f2, f3, u0, dst);
    unc_one<1>(a, k, f0, f1, f2, f3, u2, dst);
    unc_one<2>(a, k, f0, f1, f2, f3, u2, dst);
    unc_one<3>(a, k, f0, f1, f2, f3, u4, dst);
  }
}

// ---------------- k_edge6: sequential rr/sr/nlist streams + unc3 gather ----------------
__global__ __launch_bounds__(256) void k_edge6(
    const int* __restrict__ start, const int* __restrict__ nlist,
    const float* __restrict__ u0, const float* __restrict__ u2,
    const float* __restrict__ u4,
    const unsigned short* __restrict__ rad2, const unsigned short* __restrict__ S2v,
    const unsigned* __restrict__ unc3, unsigned short* __restrict__ ccg) {
  __shared__ float buf[4][1408];
  __shared__ float Ush[707];
  int a = blockIdx.x;
  int tid = threadIdx.x;
  int wv = tid >> 6;
  int k = tid & 31;
  int strm = tid >> 5;
  // stage U into LDS (1 + 81 + 625)
  for (int idx = tid; idx < 707; idx += 256)
    Ush[idx] = (idx == 0) ? u0[0] : (idx < 82 ? u2[idx - 1] : u4[idx - 82]);
  int beg = start[a], end = start[a + 1];
  int q9  = (k < 9)  ? k : 8;
  int q25 = (k < 25) ? k : 24;

  float acc[44];
#pragma unroll
  for (int j = 0; j < 44; ++j) acc[j] = 0.f;

  int i = beg + strm;
  int neC = 0;
  if (i < end) neC = nlist[i];
  while (i < end) {
    int i2 = i + 8;
    int neN = (i2 < end) ? nlist[i2] : 0;

    const unsigned short* rr = rad2 + (size_t)i * 352;
    const unsigned short* sr = S2v + (size_t)i * 168;
    const unsigned* fr = unc3 + (size_t)neC * 768;

    float rv0 = bu2f(rr[k]);
    unsigned u1 = *reinterpret_cast<const unsigned*>(rr + 32 + 2 * k);
    uint2 u2v = *reinterpret_cast<const uint2*>(rr + 96 + 4 * k);
    uint2 u3v = *reinterpret_cast<const uint2*>(rr + 224 + 4 * k);

    float s0v = bu2f(sr[0]);
    unsigned su1 = *reinterpret_cast<const unsigned*>(sr + 2 + 2 * q9);
    uint2 su2 = *reinterpret_cast<const uint2*>(sr + 24 + 4 * q9);
    uint2 su3 = *reinterpret_cast<const uint2*>(sr + 64 + 4 * q25);

    unsigned fd0 = fr[k];
    unsigned fu1[5], fu2[5], fu3[13];
#pragma unroll
    for (int j = 0; j < 5; ++j) fu1[j] = fr[32 + j * 32 + k];
#pragma unroll
    for (int j = 0; j < 5; ++j) fu2[j] = fr[192 + j * 32 + k];
#pragma unroll
    for (int j = 0; j < 13; ++j) fu3[j] = fr[352 + j * 32 + k];

    // l0
    acc[0] += rv0 * s0v * lo2f(fd0);

    // l1
    {
      float ra = lo2f(u1), rb_ = hi2f(u1);
      float V[9];
#pragma unroll
      for (int q = 0; q < 9; ++q) {
        unsigned s = (unsigned)__shfl((int)su1, q, 32);
        V[q] = ra * lo2f(s) + rb_ * hi2f(s);
      }
#pragma unroll
      for (int i3 = 0; i3 < 3; ++i3)
#pragma unroll
        for (int j3 = 0; j3 < 3; ++j3) {
          float c = 0.f;
#pragma unroll
          for (int t = 0; t < 3; ++t) {
            int idx = t * 3 + j3;
            float F = (idx & 1) ? hi2f(fu1[idx >> 1]) : lo2f(fu1[idx >> 1]);
            c += V[i3 * 3 + t] * F;
          }
          acc[1 + i3 * 3 + j3] += c;
        }
    }
    // l2
    {
      float ra = lo2f(u2v.x), rb_ = hi2f(u2v.x), rc = lo2f(u2v.y);
      float V[9];
#pragma unroll
      for (int q = 0; q < 9; ++q) {
        unsigned sx = (unsigned)__shfl((int)su2.x, q, 32);
        unsigned sy = (unsigned)__shfl((int)su2.y, q, 32);
        V[q] = ra * lo2f(sx) + rb_ * hi2f(sx) + rc * lo2f(sy);
      }
#pragma unroll
      for (int i3 = 0; i3 < 3; ++i3)
#pragma unroll
        for (int j3 = 0; j3 < 3; ++j3) {
          float c = 0.f;
#pragma unroll
          for (int t = 0; t < 3; ++t) {
            int idx = t * 3 + j3;
            float F = (idx & 1) ? hi2f(fu2[idx >> 1]) : lo2f(fu2[idx >> 1]);
            c += V[i3 * 3 + t] * F;
          }
          acc[10 + i3 * 3 + j3] += c;
        }
    }
    // l3
    {
      float ra = lo2f(u3v.x), rb_ = hi2f(u3v.x), rc = lo2f(u3v.y), rd = hi2f(u3v.y);
      float V[25];
#pragma unroll
      for (int q = 0; q < 25; ++q) {
        unsigned sx = (unsigned)__shfl((int)su3.x, q, 32);
        unsigned sy = (unsigned)__shfl((int)su3.y, q, 32);
        V[q] = ra * lo2f(sx) + rb_ * hi2f(sx) + rc * lo2f(sy) + rd * hi2f(sy);
      }
#pragma unroll
      for (int i5 = 0; i5 < 5; ++i5)
#pragma unroll
        for (int j5 = 0; j5 < 5; ++j5) {
          float c = 0.f;
#pragma unroll
          for (int t = 0; t < 5; ++t) {
            int idx = t * 5 + j5;
            float F = (idx & 1) ? hi2f(fu3[idx >> 1]) : lo2f(fu3[idx >> 1]);
            c += V[i5 * 5 + t] * F;
          }
          acc[19 + i5 * 5 + j5] += c;
        }
    }

    i = i2; neC = neN;
  }
#pragma unroll
  for (int j = 0; j < 44; ++j) acc[j] += __shfl_xor(acc[j], 32);

  if ((tid & 32) == 0) {
#pragma unroll
    for (int l = 0; l < 4; ++l) {
      int T2 = (cPL[l] + 1) * (cPL[l] + 1);
      for (int q = 0; q < T2; ++q)
        buf[wv][cSOFF[l] + q * 32 + k] = acc[cAOF[l] + q];
    }
  }
  __syncthreads();
  for (int idx = tid; idx < 1408; idx += 256)
    buf[0][idx] = (buf[0][idx] + buf[1][idx]) + (buf[2][idx] + buf[3][idx]);
  __syncthreads();
  unsigned short* crow = ccg + (size_t)a * 960;
  for (int idx = tid; idx < 960; idx += 256) {
    int kk = idx & 31, combo = idx >> 5;
    int l = c_tl[combo], mm = c_tmm[combo], s = c_ts[combo];
    int lp = l + s;
    int Ts = c_pl_r[lp] + 1;
    int Ts2 = Ts * Ts;
    const float* U = &Ush[c_ubase[lp]];
    const float* pr = &buf[0][c_soff_r[lp]];
    int m = l * l + mm;
    float sacc = 0.f;
    for (int q = 0; q < Ts2; ++q) sacc += U[q * Ts2 + m] * pr[q * 32 + kk];
    crow[idx] = f2bu(sacc);
  }
}

// ---------------- k_out2: MFMA GEMM  out = feats + concat @ Wl ----------------
template <int l>
DEV void out_body(const float* __restrict__ ft, const float* __restrict__ wl,
                  const unsigned short* __restrict__ ccg, float* __restrict__ out,
                  int rt, int tid) {
  constexpr int NMM = 2 * l + 1;
  constexpr int K   = cK[l];
  constexpr int NKS = K / 32;
  constexpr int M   = N_ATOMS * NMM;
  constexpr int NET = (l <= 1) ? 4 : (l == 2 ? 2 : 1);
  int wv = tid >> 6, lane = tid & 63;
  int c0, et0;
  bool active = true;
  if constexpr (l == 0)      { c0 = wv * 32;       et0 = 0; }
  else if constexpr (l == 1) { c0 = wv * 32;       et0 = 0; active = (wv < 3); }
  else if constexpr (l == 2) { c0 = (wv & 1) * 32; et0 = (wv >> 1) * 2; }
  else                       { c0 = 0;             et0 = wv; }
  if (!active) return;
  int ln15 = lane & 15, lhi = lane >> 4;
  int r0 = rt * 64;
  short8 Bf[2][NKS];
#pragma unroll
  for (int ct = 0; ct < 2; ++ct)
#pragma unroll
    for (int ks = 0; ks < NKS; ++ks) {
      int col = c0 + ct * 16 + ln15;
      int kb  = ks * 32 + lhi * 8;
#pragma unroll
      for (int i = 0; i < 8; ++i)
        Bf[ct][ks][i] = f2bs(wl[(long)(kb + i) * K + col]);
    }
  long abase[NET];
#pragma unroll
  for (int et = 0; et < NET; ++et) {
    int R = r0 + (et0 + et) * 16 + ln15;
    if (R >= M) R = M - 1;
    int a = R / NMM, mm = R - a * NMM;
    abase[et] = (long)a * 960 + cCB[l] + (long)mm * K;
  }
  f32x4 acc[NET][2];
#pragma unroll
  for (int et = 0; et < NET; ++et)
#pragma unroll
    for (int ct = 0; ct < 2; ++ct) acc[et][ct] = (f32x4){0.f, 0.f, 0.f, 0.f};
#pragma unroll
  for (int et = 0; et < NET; ++et) {
#pragma unroll
    for (int ks = 0; ks < NKS; ++ks) {
      short8 Af = *reinterpret_cast<const short8*>(&ccg[abase[et] + ks * 32 + lhi * 8]);
      acc[et][0] = __builtin_amdgcn_mfma_f32_16x16x32_bf16(Af, Bf[0][ks], acc[et][0], 0, 0, 0);
      acc[et][1] = __builtin_amdgcn_mfma_f32_16x16x32_bf16(Af, Bf[1][ks], acc[et][1], 0, 0, 0);
    }
  }
#pragma unroll
  for (int et = 0; et < NET; ++et)
#pragma unroll
    for (int ct = 0; ct < 2; ++ct)
#pragma unroll
      for (int r = 0; r < 4; ++r) {
        int R = r0 + (et0 + et) * 16 + lhi * 4 + r;
        if (R < M) {
          int col = c0 + ct * 16 + ln15;
          long o = (long)R * K + col;
          out[cOUT[l] + o] = ft[o] + acc[et][ct][r];
        }
      }
}

__global__ __launch_bounds__(256) void k_out2(
    const float* __restrict__ f0, const float* __restrict__ f1,
    const float* __restrict__ f2, const float* __restrict__ f3,
    const float* __restrict__ wl0, const float* __restrict__ wl1,
    const float* __restrict__ wl2, const float* __restrict__ wl3,
    const unsigned short* __restrict__ ccg, float* __restrict__ out) {
  int b = blockIdx.x;
  int tid = threadIdx.x;
  if      (b < 40)  out_body<0>(f0, wl0, ccg, out, b,       tid);
  else if (b < 158) out_body<1>(f1, wl1, ccg, out, b - 40,  tid);
  else if (b < 354) out_body<2>(f2, wl2, ccg, out, b - 158, tid);
  else              out_body<3>(f3, wl3, ccg, out, b - 354, tid);
}

// ---------------- launch ----------------
extern "C" void kernel_launch(void* const* d_in, const int* in_sizes, int n_in,
                              void* d_out, int out_size, void* d_ws, size_t ws_size,
                              hipStream_t stream) {
  (void)n_in; (void)out_size; (void)ws_size;
  bool dictord = (in_sizes[1] == 40000);
  const float* rb[4]; const float* sph[4]; const float* ft[4];
  const float *w1[4], *w2[4], *wl[4];
  for (int l = 0; l < 4; ++l) {
    if (dictord) {
      rb[l]  = (const float*)d_in[3 * l + 0];
      sph[l] = (const float*)d_in[3 * l + 1];
      ft[l]  = (const float*)d_in[3 * l + 2];
      w1[l]  = (const float*)d_in[17 + 3 * l];
      w2[l]  = (const float*)d_in[18 + 3 * l];
      wl[l]  = (const float*)d_in[19 + 3 * l];
    } else {
      rb[l]  = (const float*)d_in[l];
      sph[l] = (const float*)d_in[4 + l];
      ft[l]  = (const float*)d_in[8 + l];
      w1[l]  = (const float*)d_in[17 + l];
      w2[l]  = (const float*)d_in[21 + l];
      wl[l]  = (const float*)d_in[25 + l];
    }
  }
  const int* centers   = (const int*)d_in[12];
  const int* neighbors = (const int*)d_in[13];
  const float* u0 = (const float*)d_in[14];
  const float* u2 = (const float*)d_in[15];
  const float* u4 = (const float*)d_in[16];

  float* ws = (float*)d_ws;
  unsigned short* rad2 = (unsigned short*)(ws + RAD2_OFF);
  unsigned short* S2v  = (unsigned short*)(ws + S2_OFF);
  unsigned*       unc3 = (unsigned*)(ws + UNC3_OFF);
  unsigned short* ccg  = (unsigned short*)(ws + CCG_OFF);
  int* cnt   = (int*)(ws + CNT_OFF);
  int* start = (int*)(ws + START_OFF);
  int* fill  = (int*)(ws + FILL_OFF);
  int* inv   = (int*)(ws + INV_OFF);
  int* nlist = (int*)(ws + NLIST_OFF);

  hipMemsetAsync(cnt, 0, N_ATOMS * sizeof(int), stream);
  k_count<<<157, 256, 0, stream>>>(centers, cnt);
  k_scan<<<1, 256, 0, stream>>>(cnt, start, fill);
  k_fill<<<157, 256, 0, stream>>>(centers, neighbors, fill, inv, nlist);
  k_mid<<<7813, 256, 0, stream>>>(rb[0], rb[1], rb[2], rb[3],
                                  sph[0], sph[1], sph[2], sph[3],
                                  ft[0], ft[1], ft[2], ft[3],
                                  w1[0], w1[1], w1[2], w1[3],
                                  w2[0], w2[1], w2[2], w2[3],
                                  u0, u2, u4, inv, rad2, S2v, unc3);
  k_edge6<<<N_ATOMS, 256, 0, stream>>>(start, nlist, u0, u2, u4,
                                       rad2, S2v, unc3, ccg);
  k_out2<<<628, 256, 0, stream>>>(ft[0], ft[1], ft[2], ft[3],
                                  wl[0], wl[1], wl[2], wl[3], ccg, (float*)d_out);
}

// Round 13
// 142.647 us; speedup vs baseline: 1.8071x; 1.0179x over previous
//
#include <hip/hip_runtime.h>
#include <hip/hip_bf16.h>

typedef __hip_bfloat16 bf16;
using short8 = __attribute__((ext_vector_type(8))) short;
using f32x4  = __attribute__((ext_vector_type(4))) float;

#define DEV static __device__ __forceinline__

DEV unsigned short f2bu(float f) {
  union { bf16 h; unsigned short u; } v; v.h = __float2bfloat16(f); return v.u;
}
DEV short f2bs(float f) {
  union { bf16 h; short s; } v; v.h = __float2bfloat16(f); return v.s;
}
DEV float bu2f(unsigned short u) {
  union { unsigned x; float f; } v; v.x = ((unsigned)u) << 16; return v.f;
}
DEV float lo2f(unsigned u) { union { unsigned x; float f; } v; v.x = u << 16; return v.f; }
DEV float hi2f(unsigned u) { union { unsigned x; float f; } v; v.x = u & 0xFFFF0000u; return v.f; }
DEV unsigned pk2(float a, float b) { return (unsigned)f2bu(a) | ((unsigned)f2bu(b) << 16); }

// ---- problem constants ----
#define N_ATOMS 2500
#define N_EDGES 40000

constexpr int cK[4]    = {128, 96, 64, 32};
constexpr int cPL[4]   = {0, 2, 2, 4};
constexpr int cLO[4]   = {96, 64, 32, 0};
constexpr int cSOFF[4] = {0, 32, 320, 608};
constexpr int cAOF[4]  = {0, 1, 10, 19};
// ws float-offsets
constexpr int RAD2_OFF = 53248;                        // [pos][352 ushorts] (elist order)
constexpr int S2_OFF   = RAD2_OFF + N_EDGES * 176;     // [pos][168 ushorts] (elist order)
constexpr int UNC3_OFF = S2_OFF + N_EDGES * 84;        // [a][768 dwords]
constexpr int CCG_OFF  = UNC3_OFF + N_ATOMS * 768;     // [a][960 bf16]
constexpr int CSR_OFF   = CCG_OFF + N_ATOMS * 480;
constexpr int CNT_OFF   = CSR_OFF;
constexpr int START_OFF = CSR_OFF + 2500;
constexpr int FILL_OFF  = CSR_OFF + 5008;
constexpr int INV_OFF   = CSR_OFF + 47512;             // [e] -> pos
constexpr int NLIST_OFF = CSR_OFF + 87512;             // [pos] -> neighbor atom

constexpr int cCB[4]  = {0, 128, 416, 736};
constexpr int cOUT[4] = {0, 320000, 1040000, 1840000};

// couple/concat combo tables (constexpr for compile-time folding)
constexpr int ccl[30] = {0,0,0,0, 1,1,1,1,1,1,1,1,1, 2,2,2,2,2,2,2,2,2,2, 3,3,3,3,3,3,3};
constexpr int ccm[30] = {0,0,0,0, 0,0,0,1,1,1,2,2,2, 0,0,1,1,2,2,3,3,4,4, 0,1,2,3,4,5,6};
constexpr int ccs[30] = {0,1,2,3, 0,1,2,0,1,2,0,1,2, 0,1,0,1,0,1,0,1,0,1, 0,0,0,0,0,0,0};

// ---------------- k_count ----------------
__global__ __launch_bounds__(256) void k_count(const int* __restrict__ centers, int* __restrict__ cnt) {
  int e = blockIdx.x * 256 + threadIdx.x;
  if (e < N_EDGES) atomicAdd(&cnt[centers[e]], 1);
}

// ---------------- k_scan ----------------
__global__ __launch_bounds__(256) void k_scan(const int* __restrict__ cnt,
                                              int* __restrict__ start, int* __restrict__ fill) {
  __shared__ int part[256];
  int t = threadIdx.x;
  int loc[10];
  int s = 0;
  int base = t * 10;
#pragma unroll
  for (int i = 0; i < 10; ++i) {
    int c = (base + i < N_ATOMS) ? cnt[base + i] : 0;
    loc[i] = s; s += c;
  }
  part[t] = s;
  __syncthreads();
  for (int off = 1; off < 256; off <<= 1) {
    int v = part[t];
    if (t >= off) v += part[t - off];
    __syncthreads();
    part[t] = v;
    __syncthreads();
  }
  int excl = (t == 0) ? 0 : part[t - 1];
#pragma unroll
  for (int i = 0; i < 10; ++i) {
    if (base + i < N_ATOMS) {
      start[base + i] = excl + loc[i];
      fill[base + i]  = excl + loc[i];
    }
  }
  if (t == 255) start[N_ATOMS] = part[255];
}

// ---------------- k_fill: elist-order mapping + neighbor list ----------------
__global__ __launch_bounds__(256) void k_fill(const int* __restrict__ centers,
                                              const int* __restrict__ neighbors,
                                              int* __restrict__ fill,
                                              int* __restrict__ inv, int* __restrict__ nlist) {
  int e = blockIdx.x * 256 + threadIdx.x;
  if (e >= N_EDGES) return;
  int pos = atomicAdd(&fill[centers[e]], 1);
  inv[e] = pos;
  nlist[pos] = neighbors[e];
}

// ---------------- k_mid pieces ----------------
DEV void sph_body(int e, int q,
                  const float* __restrict__ s0p, const float* __restrict__ s1p,
                  const float* __restrict__ s2p, const float* __restrict__ s3p,
                  const float* __restrict__ u0, const float* __restrict__ u2,
                  const float* __restrict__ u4, const int* __restrict__ inv,
                  unsigned short* __restrict__ S2v) {
  float sp0 = s0p[e];
  float sp1[3], sp2[5], sp3[7];
#pragma unroll
  for (int m = 0; m < 3; ++m) sp1[m] = s1p[(long)e * 3 + m];
#pragma unroll
  for (int m = 0; m < 5; ++m) sp2[m] = s2p[(long)e * 5 + m];
#pragma unroll
  for (int m = 0; m < 7; ++m) sp3[m] = s3p[(long)e * 7 + m];
  unsigned short* out = S2v + (size_t)inv[e] * 168;
  if (q < 9) {
    const float* r = u2 + q * 9;
    float s0 = r[0] * sp0;
    float s1 = r[1] * sp1[0] + r[2] * sp1[1] + r[3] * sp1[2];
    float s2 = r[4] * sp2[0] + r[5] * sp2[1] + r[6] * sp2[2] + r[7] * sp2[3] + r[8] * sp2[4];
    *reinterpret_cast<unsigned*>(out + 2 + 2 * q) = pk2(s0, s1);
    *reinterpret_cast<unsigned*>(out + 24 + 4 * q) = pk2(s0, s1);
    out[24 + 4 * q + 2] = f2bu(s2);
    out[24 + 4 * q + 3] = 0;
  }
  if (q < 25) {
    const float* r = u4 + q * 25;
    float w0 = r[0] * sp0;
    float w1 = r[1] * sp1[0] + r[2] * sp1[1] + r[3] * sp1[2];
    float w2 = r[4] * sp2[0] + r[5] * sp2[1] + r[6] * sp2[2] + r[7] * sp2[3] + r[8] * sp2[4];
    float w3 = 0.f;
#pragma unroll
    for (int m = 0; m < 7; ++m) w3 += r[9 + m] * sp3[m];
    *reinterpret_cast<unsigned*>(out + 64 + 4 * q)     = pk2(w0, w1);
    *reinterpret_cast<unsigned*>(out + 64 + 4 * q + 2) = pk2(w2, w3);
  }
  if (q == 31) out[0] = f2bu(u0[0] * sp0);
}

template <int l>
DEV void radial_body(const float* __restrict__ rb, const float* __restrict__ Wr1f,
                     const float* __restrict__ w2, const int* __restrict__ inv,
                     unsigned short* __restrict__ rad2,
                     int e0, int tid, unsigned short (*H)[72]) {
  constexpr int NM = (l == 0) ? 8 : (l == 1) ? 6 : (l == 2) ? 4 : 2;
  constexpr int K  = cK[l];
  {
    int e  = e0 + (tid & 63);
    int j0 = (tid >> 6) * 16;
    float rbv[NM];
#pragma unroll
    for (int n = 0; n < NM; ++n) rbv[n] = rb[(long)e * NM + n];
    float h[16];
#pragma unroll
    for (int j = 0; j < 16; ++j) h[j] = 0.f;
#pragma unroll
    for (int n = 0; n < NM; ++n) {
      float rv = rbv[n];
      const float4* wp = reinterpret_cast<const float4*>(Wr1f + n * 64 + j0);
#pragma unroll
      for (int qq = 0; qq < 4; ++qq) {
        float4 w = wp[qq];
        h[4 * qq + 0] += rv * w.x;
        h[4 * qq + 1] += rv * w.y;
        h[4 * qq + 2] += rv * w.z;
        h[4 * qq + 3] += rv * w.w;
      }
    }
    unsigned short* hrow = H[tid & 63];
#pragma unroll
    for (int j = 0; j < 16; j += 2) {
      float a0 = h[j], a1 = h[j + 1];
      a0 = a0 * (1.0f / (1.0f + __expf(-a0)));
      a1 = a1 * (1.0f / (1.0f + __expf(-a1)));
      *reinterpret_cast<unsigned*>(&hrow[j0 + j]) = pk2(a0, a1);
    }
  }
  __syncthreads();
  int wv = tid >> 6, lane = tid & 63;
  constexpr int NET = (l <= 1) ? 4 : (l == 2 ? 2 : 1);
  int c0, et0;
  bool active = true;
  if constexpr (l == 0)      { c0 = wv * 32;       et0 = 0; }
  else if constexpr (l == 1) { c0 = wv * 32;       et0 = 0; active = (wv < 3); }
  else if constexpr (l == 2) { c0 = (wv & 1) * 32; et0 = (wv >> 1) * 2; }
  else                       { c0 = 0;             et0 = wv; }
  if (!active) return;
  int ln15 = lane & 15, lhi = lane >> 4;
  short8 Bf[2][2];
#pragma unroll
  for (int ct = 0; ct < 2; ++ct)
#pragma unroll
    for (int ks = 0; ks < 2; ++ks) {
      int col = c0 + ct * 16 + ln15;
      int kb  = ks * 32 + lhi * 8;
#pragma unroll
      for (int i = 0; i < 8; ++i)
        Bf[ct][ks][i] = f2bs(w2[(long)(kb + i) * K + col]);
    }
  int rowp[NET][4];
#pragma unroll
  for (int et = 0; et < NET; ++et)
#pragma unroll
    for (int r = 0; r < 4; ++r)
      rowp[et][r] = inv[e0 + (et0 + et) * 16 + lhi * 4 + r];
  f32x4 acc[NET][2];
#pragma unroll
  for (int et = 0; et < NET; ++et)
#pragma unroll
    for (int ct = 0; ct < 2; ++ct) acc[et][ct] = (f32x4){0.f, 0.f, 0.f, 0.f};
#pragma unroll
  for (int et = 0; et < NET; ++et) {
#pragma unroll
    for (int ks = 0; ks < 2; ++ks) {
      short8 Af = *reinterpret_cast<const short8*>(&H[(et0 + et) * 16 + ln15][ks * 32 + lhi * 8]);
      acc[et][0] = __builtin_amdgcn_mfma_f32_16x16x32_bf16(Af, Bf[0][ks], acc[et][0], 0, 0, 0);
      acc[et][1] = __builtin_amdgcn_mfma_f32_16x16x32_bf16(Af, Bf[1][ks], acc[et][1], 0, 0, 0);
    }
  }
#pragma unroll
  for (int ct = 0; ct < 2; ++ct) {
    int c = c0 + ct * 16 + ln15;
    int lsec = 3 - (c >> 5);
    int kk = c & 31;
    int sec  = (lsec == 0) ? 0 : (lsec == 1) ? 32 : (lsec == 2) ? 96 : 224;
    int slot = (lsec >= 2) ? 4 : ((lsec == 1) ? 2 : 1);
    int off = sec + slot * kk + l;
#pragma unroll
    for (int et = 0; et < NET; ++et)
#pragma unroll
      for (int r = 0; r < 4; ++r)
        rad2[(size_t)rowp[et][r] * 352 + off] = f2bu(acc[et][ct][r]);
  }
}

template <int l>
DEV void unc_one(int a, int k,
                 const float* __restrict__ f0, const float* __restrict__ f1,
                 const float* __restrict__ f2, const float* __restrict__ f3,
                 const float* __restrict__ U, unsigned* __restrict__ dst) {
  constexpr int T2 = (cPL[l] + 1) * (cPL[l] + 1);
  constexpr int M = (l + 1) * (l + 1);
  constexpr int NB = (T2 + 1) / 2;
  constexpr int base = (l == 0) ? 0 : (l == 1) ? 32 : (l == 2) ? 192 : 352;
  const float* fps[4] = {f0, f1, f2, f3};
  float fc[M];
#pragma unroll
  for (int lp = 0; lp <= l; ++lp) {
    const float* fp = fps[lp];
#pragma unroll
    for (int mm = 0; mm < 2 * lp + 1; ++mm)
      fc[lp * lp + mm] = fp[((long)a * (2 * lp + 1) + mm) * cK[lp] + cLO[l] + k];
  }
  float v[T2];
#pragma unroll
  for (int q = 0; q < T2; ++q) {
    float s = 0.f;
#pragma unroll
    for (int m = 0; m < M; ++m) s += U[q * T2 + m] * fc[m];
    v[q] = s;
  }
#pragma unroll
  for (int q2 = 0; q2 < NB; ++q2) {
    float a0 = v[2 * q2];
    float a1 = (2 * q2 + 1 < T2) ? v[2 * q2 + 1] : 0.f;
    dst[base + q2 * 32 + k] = pk2(a0, a1);
  }
}

// sph(5000) | radial(2500) | uncfeat(313)
__global__ __launch_bounds__(256) void k_mid(
    const float* __restrict__ rb0, const float* __restrict__ rb1,
    const float* __restrict__ rb2, const float* __restrict__ rb3,
    const float* __restrict__ s0p, const float* __restrict__ s1p,
    const float* __restrict__ s2p, const float* __restrict__ s3p,
    const float* __restrict__ f0, const float* __restrict__ f1,
    const float* __restrict__ f2, const float* __restrict__ f3,
    const float* __restrict__ w10, const float* __restrict__ w11,
    const float* __restrict__ w12, const float* __restrict__ w13,
    const float* __restrict__ w20, const float* __restrict__ w21,
    const float* __restrict__ w22, const float* __restrict__ w23,
    const float* __restrict__ u0, const float* __restrict__ u2,
    const float* __restrict__ u4, const int* __restrict__ inv,
    unsigned short* __restrict__ rad2, unsigned short* __restrict__ S2v,
    unsigned* __restrict__ unc3) {
  __shared__ __align__(16) unsigned short H[64][72];
  int b = blockIdx.x;
  int tid = threadIdx.x;
  if (b < 5000) {
    int e = b * 8 + (tid >> 5);
    sph_body(e, tid & 31, s0p, s1p, s2p, s3p, u0, u2, u4, inv, S2v);
  } else if (b < 7500) {
    int rbk = b - 5000;
    int l = rbk / 625;
    int e0 = (rbk - l * 625) * 64;
    switch (l) {
      case 0: radial_body<0>(rb0, w10, w20, inv, rad2, e0, tid, H); break;
      case 1: radial_body<1>(rb1, w11, w21, inv, rad2, e0, tid, H); break;
      case 2: radial_body<2>(rb2, w12, w22, inv, rad2, e0, tid, H); break;
      default: radial_body<3>(rb3, w13, w23, inv, rad2, e0, tid, H); break;
    }
  } else {
    int a = (b - 7500) * 8 + (tid >> 5);
    if (a >= N_ATOMS) return;
    int k = tid & 31;
    unsigned* dst = unc3 + (size_t)a * 768;
    unc_one<0>(a, k, f0, f1, f2, f3, u0, dst);
    unc_one<1>(a, k, f0, f1, f2, f3, u2, dst);
    unc_one<2>(a, k, f0, f1, f2, f3, u2, dst);
    unc_one<3>(a, k, f0, f1, f2, f3, u4, dst);
  }
}

// ---------------- k_edge7: wave-per-atom, register-only couple epilogue ----------------
template <int C>
DEV void couple_one(const float* __restrict__ Ush, const float* __restrict__ acc,
                    unsigned short* __restrict__ crow, int kk) {
  constexpr int l  = ccl[C];
  constexpr int mm = ccm[C];
  constexpr int lp = l + ccs[C];
  constexpr int T  = cPL[lp] + 1;
  constexpr int T2 = T * T;
  constexpr int m  = l * l + mm;
  constexpr int ub = (lp == 0) ? 0 : (lp == 3 ? 82 : 1);
  float s = 0.f;
#pragma unroll
  for (int q = 0; q < T2; ++q)
    s += Ush[ub + q * T2 + m] * acc[cAOF[lp] + q];
  crow[C * 32 + kk] = f2bu(s);
}

template <int C0, int C1>
DEV void couple_range(const float* __restrict__ Ush, const float* __restrict__ acc,
                      unsigned short* __restrict__ crow, int kk) {
  if constexpr (C0 < C1) {
    couple_one<C0>(Ush, acc, crow, kk);
    couple_range<C0 + 1, C1>(Ush, acc, crow, kk);
  }
}

__global__ __launch_bounds__(256) void k_edge7(
    const int* __restrict__ start, const int* __restrict__ nlist,
    const float* __restrict__ u0, const float* __restrict__ u2,
    const float* __restrict__ u4,
    const unsigned short* __restrict__ rad2, const unsigned short* __restrict__ S2v,
    const unsigned* __restrict__ unc3, unsigned short* __restrict__ ccg) {
  __shared__ float Ush[707];
  int tid = threadIdx.x;
  for (int idx = tid; idx < 707; idx += 256)
    Ush[idx] = (idx == 0) ? u0[0] : (idx < 82 ? u2[idx - 1] : u4[idx - 82]);
  __syncthreads();
  int wv = tid >> 6;
  int lane = tid & 63;
  int k = lane & 31;
  int strm = lane >> 5;          // 2 streams per wave
  int a = blockIdx.x * 4 + wv;   // one atom per wave
  int beg = start[a], end = start[a + 1];
  int q9  = (k < 9)  ? k : 8;
  int q25 = (k < 25) ? k : 24;

  float acc[44];
#pragma unroll
  for (int j = 0; j < 44; ++j) acc[j] = 0.f;

  int i = beg + strm;
  int neC = 0;
  if (i < end) neC = nlist[i];
  while (i < end) {
    int i2 = i + 2;
    int neN = (i2 < end) ? nlist[i2] : 0;

    const unsigned short* rr = rad2 + (size_t)i * 352;
    const unsigned short* sr = S2v + (size_t)i * 168;
    const unsigned* fr = unc3 + (size_t)neC * 768;

    float rv0 = bu2f(rr[k]);
    unsigned u1 = *reinterpret_cast<const unsigned*>(rr + 32 + 2 * k);
    uint2 u2v = *reinterpret_cast<const uint2*>(rr + 96 + 4 * k);
    uint2 u3v = *reinterpret_cast<const uint2*>(rr + 224 + 4 * k);

    float s0v = bu2f(sr[0]);
    unsigned su1 = *reinterpret_cast<const unsigned*>(sr + 2 + 2 * q9);
    uint2 su2 = *reinterpret_cast<const uint2*>(sr + 24 + 4 * q9);
    uint2 su3 = *reinterpret_cast<const uint2*>(sr + 64 + 4 * q25);

    unsigned fd0 = fr[k];
    unsigned fu1[5], fu2[5], fu3[13];
#pragma unroll
    for (int j = 0; j < 5; ++j) fu1[j] = fr[32 + j * 32 + k];
#pragma unroll
    for (int j = 0; j < 5; ++j) fu2[j] = fr[192 + j * 32 + k];
#pragma unroll
    for (int j = 0; j < 13; ++j) fu3[j] = fr[352 + j * 32 + k];

    // l0
    acc[0] += rv0 * s0v * lo2f(fd0);

    // l1
    {
      float ra = lo2f(u1), rb_ = hi2f(u1);
      float V[9];
#pragma unroll
      for (int q = 0; q < 9; ++q) {
        unsigned s = (unsigned)__shfl((int)su1, q, 32);
        V[q] = ra * lo2f(s) + rb_ * hi2f(s);
      }
#pragma unroll
      for (int i3 = 0; i3 < 3; ++i3)
#pragma unroll
        for (int j3 = 0; j3 < 3; ++j3) {
          float c = 0.f;
#pragma unroll
          for (int t = 0; t < 3; ++t) {
            int idx = t * 3 + j3;
            float F = (idx & 1) ? hi2f(fu1[idx >> 1]) : lo2f(fu1[idx >> 1]);
            c += V[i3 * 3 + t] * F;
          }
          acc[1 + i3 * 3 + j3] += c;
        }
    }
    // l2
    {
      float ra = lo2f(u2v.x), rb_ = hi2f(u2v.x), rc = lo2f(u2v.y);
      float V[9];
#pragma unroll
      for (int q = 0; q < 9; ++q) {
        unsigned sx = (unsigned)__shfl((int)su2.x, q, 32);
        unsigned sy = (unsigned)__shfl((int)su2.y, q, 32);
        V[q] = ra * lo2f(sx) + rb_ * hi2f(sx) + rc * lo2f(sy);
      }
#pragma unroll
      for (int i3 = 0; i3 < 3; ++i3)
#pragma unroll
        for (int j3 = 0; j3 < 3; ++j3) {
          float c = 0.f;
#pragma unroll
          for (int t = 0; t < 3; ++t) {
            int idx = t * 3 + j3;
            float F = (idx & 1) ? hi2f(fu2[idx >> 1]) : lo2f(fu2[idx >> 1]);
            c += V[i3 * 3 + t] * F;
          }
          acc[10 + i3 * 3 + j3] += c;
        }
    }
    // l3
    {
      float ra = lo2f(u3v.x), rb_ = hi2f(u3v.x), rc = lo2f(u3v.y), rd = hi2f(u3v.y);
      float V[25];
#pragma unroll
      for (int q = 0; q < 25; ++q) {
        unsigned sx = (unsigned)__shfl((int)su3.x, q, 32);
        unsigned sy = (unsigned)__shfl((int)su3.y, q, 32);
        V[q] = ra * lo2f(sx) + rb_ * hi2f(sx) + rc * lo2f(sy) + rd * hi2f(sy);
      }
#pragma unroll
      for (int i5 = 0; i5 < 5; ++i5)
#pragma unroll
        for (int j5 = 0; j5 < 5; ++j5) {
          float c = 0.f;
#pragma unroll
          for (int t = 0; t < 5; ++t) {
            int idx = t * 5 + j5;
            float F = (idx & 1) ? hi2f(fu3[idx >> 1]) : lo2f(fu3[idx >> 1]);
            c += V[i5 * 5 + t] * F;
          }
          acc[19 + i5 * 5 + j5] += c;
        }
    }

    i = i2; neC = neN;
  }
  // combine the two 32-lane streams; both halves end with full sums
#pragma unroll
  for (int j = 0; j < 44; ++j) acc[j] += __shfl_xor(acc[j], 32);

  // register-only couple + concat: lanes 0-31 do combos 0-14, lanes 32-63 do 15-29
  unsigned short* crow = ccg + (size_t)a * 960;
  if (lane < 32) couple_range<0, 15>(Ush, acc, crow, k);
  else           couple_range<15, 30>(Ush, acc, crow, k);
}

// ---------------- k_out2: MFMA GEMM  out = feats + concat @ Wl ----------------
template <int l>
DEV void out_body(const float* __restrict__ ft, const float* __restrict__ wl,
                  const unsigned short* __restrict__ ccg, float* __restrict__ out,
                  int rt, int tid) {
  constexpr int NMM = 2 * l + 1;
  constexpr int K   = cK[l];
  constexpr int NKS = K / 32;
  constexpr int M   = N_ATOMS * NMM;
  constexpr int NET = (l <= 1) ? 4 : (l == 2 ? 2 : 1);
  int wv = tid >> 6, lane = tid & 63;
  int c0, et0;
  bool active = true;
  if constexpr (l == 0)      { c0 = wv * 32;       et0 = 0; }
  else if constexpr (l == 1) { c0 = wv * 32;       et0 = 0; active = (wv < 3); }
  else if constexpr (l == 2) { c0 = (wv & 1) * 32; et0 = (wv >> 1) * 2; }
  else                       { c0 = 0;             et0 = wv; }
  if (!active) return;
  int ln15 = lane & 15, lhi = lane >> 4;
  int r0 = rt * 64;
  short8 Bf[2][NKS];
#pragma unroll
  for (int ct = 0; ct < 2; ++ct)
#pragma unroll
    for (int ks = 0; ks < NKS; ++ks) {
      int col = c0 + ct * 16 + ln15;
      int kb  = ks * 32 + lhi * 8;
#pragma unroll
      for (int i = 0; i < 8; ++i)
        Bf[ct][ks][i] = f2bs(wl[(long)(kb + i) * K + col]);
    }
  long abase[NET];
#pragma unroll
  for (int et = 0; et < NET; ++et) {
    int R = r0 + (et0 + et) * 16 + ln15;
    if (R >= M) R = M - 1;
    int a = R / NMM, mm = R - a * NMM;
    abase[et] = (long)a * 960 + cCB[l] + (long)mm * K;
  }
  f32x4 acc[NET][2];
#pragma unroll
  for (int et = 0; et < NET; ++et)
#pragma unroll
    for (int ct = 0; ct < 2; ++ct) acc[et][ct] = (f32x4){0.f, 0.f, 0.f, 0.f};
#pragma unroll
  for (int et = 0; et < NET; ++et) {
#pragma unroll
    for (int ks = 0; ks < NKS; ++ks) {
      short8 Af = *reinterpret_cast<const short8*>(&ccg[abase[et] + ks * 32 + lhi * 8]);
      acc[et][0] = __builtin_amdgcn_mfma_f32_16x16x32_bf16(Af, Bf[0][ks], acc[et][0], 0, 0, 0);
      acc[et][1] = __builtin_amdgcn_mfma_f32_16x16x32_bf16(Af, Bf[1][ks], acc[et][1], 0, 0, 0);
    }
  }
#pragma unroll
  for (int et = 0; et < NET; ++et)
#pragma unroll
    for (int ct = 0; ct < 2; ++ct)
#pragma unroll
      for (int r = 0; r < 4; ++r) {
        int R = r0 + (et0 + et) * 16 + lhi * 4 + r;
        if (R < M) {
          int col = c0 + ct * 16 + ln15;
          long o = (long)R * K + col;
          out[cOUT[l] + o] = ft[o] + acc[et][ct][r];
        }
      }
}

__global__ __launch_bounds__(256) void k_out2(
    const float* __restrict__ f0, const float* __restrict__ f1,
    const float* __restrict__ f2, const float* __restrict__ f3,
    const float* __restrict__ wl0, const float* __restrict__ wl1,
    const float* __restrict__ wl2, const float* __restrict__ wl3,
    const unsigned short* __restrict__ ccg, float* __restrict__ out) {
  int b = blockIdx.x;
  int tid = threadIdx.x;
  if      (b < 40)  out_body<0>(f0, wl0, ccg, out, b,       tid);
  else if (b < 158) out_body<1>(f1, wl1, ccg, out, b - 40,  tid);
  else if (b < 354) out_body<2>(f2, wl2, ccg, out, b - 158, tid);
  else              out_body<3>(f3, wl3, ccg, out, b - 354, tid);
}

// ---------------- launch ----------------
extern "C" void kernel_launch(void* const* d_in, const int* in_sizes, int n_in,
                              void* d_out, int out_size, void* d_ws, size_t ws_size,
                              hipStream_t stream) {
  (void)n_in; (void)out_size; (void)ws_size;
  bool dictord = (in_sizes[1] == 40000);
  const float* rb[4]; const float* sph[4]; const float* ft[4];
  const float *w1[4], *w2[4], *wl[4];
  for (int l = 0; l < 4; ++l) {
    if (dictord) {
      rb[l]  = (const float*)d_in[3 * l + 0];
      sph[l] = (const float*)d_in[3 * l + 1];
      ft[l]  = (const float*)d_in[3 * l + 2];
      w1[l]  = (const float*)d_in[17 + 3 * l];
      w2[l]  = (const float*)d_in[18 + 3 * l];
      wl[l]  = (const float*)d_in[19 + 3 * l];
    } else {
      rb[l]  = (const float*)d_in[l];
      sph[l] = (const float*)d_in[4 + l];
      ft[l]  = (const float*)d_in[8 + l];
      w1[l]  = (const float*)d_in[17 + l];
      w2[l]  = (const float*)d_in[21 + l];
      wl[l]  = (const float*)d_in[25 + l];
    }
  }
  const int* centers   = (const int*)d_in[12];
  const int* neighbors = (const int*)d_in[13];
  const float* u0 = (const float*)d_in[14];
  const float* u2 = (const float*)d_in[15];
  const float* u4 = (const float*)d_in[16];

  float* ws = (float*)d_ws;
  unsigned short* rad2 = (unsigned short*)(ws + RAD2_OFF);
  unsigned short* S2v  = (unsigned short*)(ws + S2_OFF);
  unsigned*       unc3 = (unsigned*)(ws + UNC3_OFF);
  unsigned short* ccg  = (unsigned short*)(ws + CCG_OFF);
  int* cnt   = (int*)(ws + CNT_OFF);
  int* start = (int*)(ws + START_OFF);
  int* fill  = (int*)(ws + FILL_OFF);
  int* inv   = (int*)(ws + INV_OFF);
  int* nlist = (int*)(ws + NLIST_OFF);

  hipMemsetAsync(cnt, 0, N_ATOMS * sizeof(int), stream);
  k_count<<<157, 256, 0, stream>>>(centers, cnt);
  k_scan<<<1, 256, 0, stream>>>(cnt, start, fill);
  k_fill<<<157, 256, 0, stream>>>(centers, neighbors, fill, inv, nlist);
  k_mid<<<7813, 256, 0, stream>>>(rb[0], rb[1], rb[2], rb[3],
                                  sph[0], sph[1], sph[2], sph[3],
                                  ft[0], ft[1], ft[2], ft[3],
                                  w1[0], w1[1], w1[2], w1[3],
                                  w2[0], w2[1], w2[2], w2[3],
                                  u0, u2, u4, inv, rad2, S2v, unc3);
  k_edge7<<<625, 256, 0, stream>>>(start, nlist, u0, u2, u4,
                                   rad2, S2v, unc3, ccg);
  k_out2<<<628, 256, 0, stream>>>(ft[0], ft[1], ft[2], ft[3],
                                  wl[0], wl[1], wl[2], wl[3], ccg, (float*)d_out);
}

// Round 14
// 125.621 us; speedup vs baseline: 2.0520x; 1.1355x over previous
//
#include <hip/hip_runtime.h>
#include <hip/hip_bf16.h>

typedef __hip_bfloat16 bf16;
using short8 = __attribute__((ext_vector_type(8))) short;
using f32x4  = __attribute__((ext_vector_type(4))) float;

#define DEV static __device__ __forceinline__

DEV unsigned short f2bu(float f) {
  union { bf16 h; unsigned short u; } v; v.h = __float2bfloat16(f); return v.u;
}
DEV short f2bs(float f) {
  union { bf16 h; short s; } v; v.h = __float2bfloat16(f); return v.s;
}
DEV float bu2f(unsigned short u) {
  union { unsigned x; float f; } v; v.x = ((unsigned)u) << 16; return v.f;
}
DEV float lo2f(unsigned u) { union { unsigned x; float f; } v; v.x = u << 16; return v.f; }
DEV float hi2f(unsigned u) { union { unsigned x; float f; } v; v.x = u & 0xFFFF0000u; return v.f; }
DEV unsigned pk2(float a, float b) { return (unsigned)f2bu(a) | ((unsigned)f2bu(b) << 16); }

// ---- problem constants ----
#define N_ATOMS 2500
#define N_EDGES 40000

constexpr int cK[4]    = {128, 96, 64, 32};
constexpr int cPL[4]   = {0, 2, 2, 4};
constexpr int cLO[4]   = {96, 64, 32, 0};
constexpr int cAOF[4]  = {0, 1, 10, 19};
// ws float-offsets
constexpr int RAD2_OFF = 53248;                        // [pos][352 ushorts]
constexpr int S2_OFF   = RAD2_OFF + N_EDGES * 176;     // [pos][168 ushorts]
constexpr int UNC3_OFF = S2_OFF + N_EDGES * 84;        // [a][768 dwords]
constexpr int CCG_OFF  = UNC3_OFF + N_ATOMS * 768;     // [a][960 bf16]
constexpr int CSR_OFF   = CCG_OFF + N_ATOMS * 480;
constexpr int CNT_OFF   = CSR_OFF;
constexpr int START_OFF = CSR_OFF + 2500;
constexpr int FILL_OFF  = CSR_OFF + 5008;
constexpr int INV_OFF   = CSR_OFF + 47512;             // [e] -> pos
constexpr int NLIST_OFF = CSR_OFF + 87512;             // [pos] -> neighbor atom

constexpr int cCB[4]  = {0, 128, 416, 736};
constexpr int cOUT[4] = {0, 320000, 1040000, 1840000};

// couple/concat combo tables (constexpr for compile-time folding)
constexpr int ccl[30] = {0,0,0,0, 1,1,1,1,1,1,1,1,1, 2,2,2,2,2,2,2,2,2,2, 3,3,3,3,3,3,3};
constexpr int ccm[30] = {0,0,0,0, 0,0,0,1,1,1,2,2,2, 0,0,1,1,2,2,3,3,4,4, 0,1,2,3,4,5,6};
constexpr int ccs[30] = {0,1,2,3, 0,1,2,0,1,2,0,1,2, 0,1,0,1,0,1,0,1,0,1, 0,0,0,0,0,0,0};

// ---------------- k_count ----------------
__global__ __launch_bounds__(256) void k_count(const int* __restrict__ centers, int* __restrict__ cnt) {
  int e = blockIdx.x * 256 + threadIdx.x;
  if (e < N_EDGES) atomicAdd(&cnt[centers[e]], 1);
}

// ---------------- k_scan ----------------
__global__ __launch_bounds__(256) void k_scan(const int* __restrict__ cnt,
                                              int* __restrict__ start, int* __restrict__ fill) {
  __shared__ int part[256];
  int t = threadIdx.x;
  int loc[10];
  int s = 0;
  int base = t * 10;
#pragma unroll
  for (int i = 0; i < 10; ++i) {
    int c = (base + i < N_ATOMS) ? cnt[base + i] : 0;
    loc[i] = s; s += c;
  }
  part[t] = s;
  __syncthreads();
  for (int off = 1; off < 256; off <<= 1) {
    int v = part[t];
    if (t >= off) v += part[t - off];
    __syncthreads();
    part[t] = v;
    __syncthreads();
  }
  int excl = (t == 0) ? 0 : part[t - 1];
#pragma unroll
  for (int i = 0; i < 10; ++i) {
    if (base + i < N_ATOMS) {
      start[base + i] = excl + loc[i];
      fill[base + i]  = excl + loc[i];
    }
  }
  if (t == 255) start[N_ATOMS] = part[255];
}

// ---------------- k_fill ----------------
__global__ __launch_bounds__(256) void k_fill(const int* __restrict__ centers,
                                              const int* __restrict__ neighbors,
                                              int* __restrict__ fill,
                                              int* __restrict__ inv, int* __restrict__ nlist) {
  int e = blockIdx.x * 256 + threadIdx.x;
  if (e >= N_EDGES) return;
  int pos = atomicAdd(&fill[centers[e]], 1);
  inv[e] = pos;
  nlist[pos] = neighbors[e];
}

// ---------------- k_mid pieces (unchanged from R12) ----------------
DEV void sph_body(int e, int q,
                  const float* __restrict__ s0p, const float* __restrict__ s1p,
                  const float* __restrict__ s2p, const float* __restrict__ s3p,
                  const float* __restrict__ u0, const float* __restrict__ u2,
                  const float* __restrict__ u4, const int* __restrict__ inv,
                  unsigned short* __restrict__ S2v) {
  float sp0 = s0p[e];
  float sp1[3], sp2[5], sp3[7];
#pragma unroll
  for (int m = 0; m < 3; ++m) sp1[m] = s1p[(long)e * 3 + m];
#pragma unroll
  for (int m = 0; m < 5; ++m) sp2[m] = s2p[(long)e * 5 + m];
#pragma unroll
  for (int m = 0; m < 7; ++m) sp3[m] = s3p[(long)e * 7 + m];
  unsigned short* out = S2v + (size_t)inv[e] * 168;
  if (q < 9) {
    const float* r = u2 + q * 9;
    float s0 = r[0] * sp0;
    float s1 = r[1] * sp1[0] + r[2] * sp1[1] + r[3] * sp1[2];
    float s2 = r[4] * sp2[0] + r[5] * sp2[1] + r[6] * sp2[2] + r[7] * sp2[3] + r[8] * sp2[4];
    *reinterpret_cast<unsigned*>(out + 2 + 2 * q) = pk2(s0, s1);
    *reinterpret_cast<unsigned*>(out + 24 + 4 * q) = pk2(s0, s1);
    out[24 + 4 * q + 2] = f2bu(s2);
    out[24 + 4 * q + 3] = 0;
  }
  if (q < 25) {
    const float* r = u4 + q * 25;
    float w0 = r[0] * sp0;
    float w1 = r[1] * sp1[0] + r[2] * sp1[1] + r[3] * sp1[2];
    float w2 = r[4] * sp2[0] + r[5] * sp2[1] + r[6] * sp2[2] + r[7] * sp2[3] + r[8] * sp2[4];
    float w3 = 0.f;
#pragma unroll
    for (int m = 0; m < 7; ++m) w3 += r[9 + m] * sp3[m];
    *reinterpret_cast<unsigned*>(out + 64 + 4 * q)     = pk2(w0, w1);
    *reinterpret_cast<unsigned*>(out + 64 + 4 * q + 2) = pk2(w2, w3);
  }
  if (q == 31) out[0] = f2bu(u0[0] * sp0);
}

template <int l>
DEV void radial_body(const float* __restrict__ rb, const float* __restrict__ Wr1f,
                     const float* __restrict__ w2, const int* __restrict__ inv,
                     unsigned short* __restrict__ rad2,
                     int e0, int tid, unsigned short (*H)[72]) {
  constexpr int NM = (l == 0) ? 8 : (l == 1) ? 6 : (l == 2) ? 4 : 2;
  constexpr int K  = cK[l];
  {
    int e  = e0 + (tid & 63);
    int j0 = (tid >> 6) * 16;
    float rbv[NM];
#pragma unroll
    for (int n = 0; n < NM; ++n) rbv[n] = rb[(long)e * NM + n];
    float h[16];
#pragma unroll
    for (int j = 0; j < 16; ++j) h[j] = 0.f;
#pragma unroll
    for (int n = 0; n < NM; ++n) {
      float rv = rbv[n];
      const float4* wp = reinterpret_cast<const float4*>(Wr1f + n * 64 + j0);
#pragma unroll
      for (int qq = 0; qq < 4; ++qq) {
        float4 w = wp[qq];
        h[4 * qq + 0] += rv * w.x;
        h[4 * qq + 1] += rv * w.y;
        h[4 * qq + 2] += rv * w.z;
        h[4 * qq + 3] += rv * w.w;
      }
    }
    unsigned short* hrow = H[tid & 63];
#pragma unroll
    for (int j = 0; j < 16; j += 2) {
      float a0 = h[j], a1 = h[j + 1];
      a0 = a0 * (1.0f / (1.0f + __expf(-a0)));
      a1 = a1 * (1.0f / (1.0f + __expf(-a1)));
      *reinterpret_cast<unsigned*>(&hrow[j0 + j]) = pk2(a0, a1);
    }
  }
  __syncthreads();
  int wv = tid >> 6, lane = tid & 63;
  constexpr int NET = (l <= 1) ? 4 : (l == 2 ? 2 : 1);
  int c0, et0;
  bool active = true;
  if constexpr (l == 0)      { c0 = wv * 32;       et0 = 0; }
  else if constexpr (l == 1) { c0 = wv * 32;       et0 = 0; active = (wv < 3); }
  else if constexpr (l == 2) { c0 = (wv & 1) * 32; et0 = (wv >> 1) * 2; }
  else                       { c0 = 0;             et0 = wv; }
  if (!active) return;
  int ln15 = lane & 15, lhi = lane >> 4;
  short8 Bf[2][2];
#pragma unroll
  for (int ct = 0; ct < 2; ++ct)
#pragma unroll
    for (int ks = 0; ks < 2; ++ks) {
      int col = c0 + ct * 16 + ln15;
      int kb  = ks * 32 + lhi * 8;
#pragma unroll
      for (int i = 0; i < 8; ++i)
        Bf[ct][ks][i] = f2bs(w2[(long)(kb + i) * K + col]);
    }
  int rowp[NET][4];
#pragma unroll
  for (int et = 0; et < NET; ++et)
#pragma unroll
    for (int r = 0; r < 4; ++r)
      rowp[et][r] = inv[e0 + (et0 + et) * 16 + lhi * 4 + r];
  f32x4 acc[NET][2];
#pragma unroll
  for (int et = 0; et < NET; ++et)
#pragma unroll
    for (int ct = 0; ct < 2; ++ct) acc[et][ct] = (f32x4){0.f, 0.f, 0.f, 0.f};
#pragma unroll
  for (int et = 0; et < NET; ++et) {
#pragma unroll
    for (int ks = 0; ks < 2; ++ks) {
      short8 Af = *reinterpret_cast<const short8*>(&H[(et0 + et) * 16 + ln15][ks * 32 + lhi * 8]);
      acc[et][0] = __builtin_amdgcn_mfma_f32_16x16x32_bf16(Af, Bf[0][ks], acc[et][0], 0, 0, 0);
      acc[et][1] = __builtin_amdgcn_mfma_f32_16x16x32_bf16(Af, Bf[1][ks], acc[et][1], 0, 0, 0);
    }
  }
#pragma unroll
  for (int ct = 0; ct < 2; ++ct) {
    int c = c0 + ct * 16 + ln15;
    int lsec = 3 - (c >> 5);
    int kk = c & 31;
    int sec  = (lsec == 0) ? 0 : (lsec == 1) ? 32 : (lsec == 2) ? 96 : 224;
    int slot = (lsec >= 2) ? 4 : ((lsec == 1) ? 2 : 1);
    int off = sec + slot * kk + l;
#pragma unroll
    for (int et = 0; et < NET; ++et)
#pragma unroll
      for (int r = 0; r < 4; ++r)
        rad2[(size_t)rowp[et][r] * 352 + off] = f2bu(acc[et][ct][r]);
  }
}

template <int l>
DEV void unc_one(int a, int k,
                 const float* __restrict__ f0, const float* __restrict__ f1,
                 const float* __restrict__ f2, const float* __restrict__ f3,
                 const float* __restrict__ U, unsigned* __restrict__ dst) {
  constexpr int T2 = (cPL[l] + 1) * (cPL[l] + 1);
  constexpr int M = (l + 1) * (l + 1);
  constexpr int NB = (T2 + 1) / 2;
  constexpr int base = (l == 0) ? 0 : (l == 1) ? 32 : (l == 2) ? 192 : 352;
  const float* fps[4] = {f0, f1, f2, f3};
  float fc[M];
#pragma unroll
  for (int lp = 0; lp <= l; ++lp) {
    const float* fp = fps[lp];
#pragma unroll
    for (int mm = 0; mm < 2 * lp + 1; ++mm)
      fc[lp * lp + mm] = fp[((long)a * (2 * lp + 1) + mm) * cK[lp] + cLO[l] + k];
  }
  float v[T2];
#pragma unroll
  for (int q = 0; q < T2; ++q) {
    float s = 0.f;
#pragma unroll
    for (int m = 0; m < M; ++m) s += U[q * T2 + m] * fc[m];
    v[q] = s;
  }
#pragma unroll
  for (int q2 = 0; q2 < NB; ++q2) {
    float a0 = v[2 * q2];
    float a1 = (2 * q2 + 1 < T2) ? v[2 * q2 + 1] : 0.f;
    dst[base + q2 * 32 + k] = pk2(a0, a1);
  }
}

// sph(5000) | radial(2500) | uncfeat(313)
__global__ __launch_bounds__(256) void k_mid(
    const float* __restrict__ rb0, const float* __restrict__ rb1,
    const float* __restrict__ rb2, const float* __restrict__ rb3,
    const float* __restrict__ s0p, const float* __restrict__ s1p,
    const float* __restrict__ s2p, const float* __restrict__ s3p,
    const float* __restrict__ f0, const float* __restrict__ f1,
    const float* __restrict__ f2, const float* __restrict__ f3,
    const float* __restrict__ w10, const float* __restrict__ w11,
    const float* __restrict__ w12, const float* __restrict__ w13,
    const float* __restrict__ w20, const float* __restrict__ w21,
    const float* __restrict__ w22, const float* __restrict__ w23,
    const float* __restrict__ u0, const float* __restrict__ u2,
    const float* __restrict__ u4, const int* __restrict__ inv,
    unsigned short* __restrict__ rad2, unsigned short* __restrict__ S2v,
    unsigned* __restrict__ unc3) {
  __shared__ __align__(16) unsigned short H[64][72];
  int b = blockIdx.x;
  int tid = threadIdx.x;
  if (b < 5000) {
    int e = b * 8 + (tid >> 5);
    sph_body(e, tid & 31, s0p, s1p, s2p, s3p, u0, u2, u4, inv, S2v);
  } else if (b < 7500) {
    int rbk = b - 5000;
    int l = rbk / 625;
    int e0 = (rbk - l * 625) * 64;
    switch (l) {
      case 0: radial_body<0>(rb0, w10, w20, inv, rad2, e0, tid, H); break;
      case 1: radial_body<1>(rb1, w11, w21, inv, rad2, e0, tid, H); break;
      case 2: radial_body<2>(rb2, w12, w22, inv, rad2, e0, tid, H); break;
      default: radial_body<3>(rb3, w13, w23, inv, rad2, e0, tid, H); break;
    }
  } else {
    int a = (b - 7500) * 8 + (tid >> 5);
    if (a >= N_ATOMS) return;
    int k = tid & 31;
    unsigned* dst = unc3 + (size_t)a * 768;
    unc_one<0>(a, k, f0, f1, f2, f3, u0, dst);
    unc_one<1>(a, k, f0, f1, f2, f3, u2, dst);
    unc_one<2>(a, k, f0, f1, f2, f3, u2, dst);
    unc_one<3>(a, k, f0, f1, f2, f3, u4, dst);
  }
}

// ---------------- k_edge8: l-split role waves, register-only epilogue ----------------
template <int C, int SHIFT>
DEV void couple_one(const float* __restrict__ Ush, const float* __restrict__ acc,
                    unsigned short* __restrict__ crow, int kk) {
  constexpr int l  = ccl[C];
  constexpr int mm = ccm[C];
  constexpr int lp = l + ccs[C];
  constexpr int T  = cPL[lp] + 1;
  constexpr int T2 = T * T;
  constexpr int m  = l * l + mm;
  constexpr int ub = (lp == 0) ? 0 : (lp == 3 ? 82 : 1);
  float s = 0.f;
#pragma unroll
  for (int q = 0; q < T2; ++q)
    s += Ush[ub + q * T2 + m] * acc[cAOF[lp] - SHIFT + q];
  crow[C * 32 + kk] = f2bu(s);
}

__global__ __launch_bounds__(256) void k_edge8(
    const int* __restrict__ start, const int* __restrict__ nlist,
    const float* __restrict__ u0, const float* __restrict__ u2,
    const float* __restrict__ u4,
    const unsigned short* __restrict__ rad2, const unsigned short* __restrict__ S2v,
    const unsigned* __restrict__ unc3, unsigned short* __restrict__ ccg) {
  __shared__ float Ush[707];
  int tid = threadIdx.x;
  for (int idx = tid; idx < 707; idx += 256)
    Ush[idx] = (idx == 0) ? u0[0] : (idx < 82 ? u2[idx - 1] : u4[idx - 82]);
  __syncthreads();
  int wv = tid >> 6;
  int lane = tid & 63;
  int k = lane & 31;
  int strm = lane >> 5;            // 2 streams per wave
  int a = blockIdx.x * 2 + (wv >> 1);
  int role = wv & 1;               // 0: l0+l1+l2 ; 1: l3
  int beg = start[a], end = start[a + 1];
  unsigned short* crow = ccg + (size_t)a * 960;

  if (role == 0) {
    int q9 = (k < 9) ? k : 8;
    float acc[19];
#pragma unroll
    for (int j = 0; j < 19; ++j) acc[j] = 0.f;
    int i = beg + strm;
    int neC = 0;
    if (i < end) neC = nlist[i];
    while (i < end) {
      int i2 = i + 2;
      int neN = (i2 < end) ? nlist[i2] : 0;
      const unsigned short* rr = rad2 + (size_t)i * 352;
      const unsigned short* sr = S2v + (size_t)i * 168;
      const unsigned* fr = unc3 + (size_t)neC * 768;

      float rv0 = bu2f(rr[k]);
      unsigned u1v = *reinterpret_cast<const unsigned*>(rr + 32 + 2 * k);
      uint2 u2v = *reinterpret_cast<const uint2*>(rr + 96 + 4 * k);
      float s0v = bu2f(sr[0]);
      unsigned su1 = *reinterpret_cast<const unsigned*>(sr + 2 + 2 * q9);
      uint2 su2 = *reinterpret_cast<const uint2*>(sr + 24 + 4 * q9);
      unsigned fd0 = fr[k];
      unsigned fu1[5], fu2[5];
#pragma unroll
      for (int j = 0; j < 5; ++j) fu1[j] = fr[32 + j * 32 + k];
#pragma unroll
      for (int j = 0; j < 5; ++j) fu2[j] = fr[192 + j * 32 + k];

      acc[0] += rv0 * s0v * lo2f(fd0);
      {
        float ra = lo2f(u1v), rb_ = hi2f(u1v);
        float V[9];
#pragma unroll
        for (int q = 0; q < 9; ++q) {
          unsigned s = (unsigned)__shfl((int)su1, q, 32);
          V[q] = ra * lo2f(s) + rb_ * hi2f(s);
        }
#pragma unroll
        for (int i3 = 0; i3 < 3; ++i3)
#pragma unroll
          for (int j3 = 0; j3 < 3; ++j3) {
            float c = 0.f;
#pragma unroll
            for (int t = 0; t < 3; ++t) {
              int idx = t * 3 + j3;
              float F = (idx & 1) ? hi2f(fu1[idx >> 1]) : lo2f(fu1[idx >> 1]);
              c += V[i3 * 3 + t] * F;
            }
            acc[1 + i3 * 3 + j3] += c;
          }
      }
      {
        float ra = lo2f(u2v.x), rb_ = hi2f(u2v.x), rc = lo2f(u2v.y);
        float V[9];
#pragma unroll
        for (int q = 0; q < 9; ++q) {
          unsigned sx = (unsigned)__shfl((int)su2.x, q, 32);
          unsigned sy = (unsigned)__shfl((int)su2.y, q, 32);
          V[q] = ra * lo2f(sx) + rb_ * hi2f(sx) + rc * lo2f(sy);
        }
#pragma unroll
        for (int i3 = 0; i3 < 3; ++i3)
#pragma unroll
          for (int j3 = 0; j3 < 3; ++j3) {
            float c = 0.f;
#pragma unroll
            for (int t = 0; t < 3; ++t) {
              int idx = t * 3 + j3;
              float F = (idx & 1) ? hi2f(fu2[idx >> 1]) : lo2f(fu2[idx >> 1]);
              c += V[i3 * 3 + t] * F;
            }
            acc[10 + i3 * 3 + j3] += c;
          }
      }
      i = i2; neC = neN;
    }
#pragma unroll
    for (int j = 0; j < 19; ++j) acc[j] += __shfl_xor(acc[j], 32);
    // couple: 14 lp<=2 combos, 7 per half-wave
    if (lane < 32) {
      couple_one<0, 0>(Ush, acc, crow, k);
      couple_one<1, 0>(Ush, acc, crow, k);
      couple_one<2, 0>(Ush, acc, crow, k);
      couple_one<4, 0>(Ush, acc, crow, k);
      couple_one<5, 0>(Ush, acc, crow, k);
      couple_one<7, 0>(Ush, acc, crow, k);
      couple_one<8, 0>(Ush, acc, crow, k);
    } else {
      couple_one<10, 0>(Ush, acc, crow, k);
      couple_one<11, 0>(Ush, acc, crow, k);
      couple_one<13, 0>(Ush, acc, crow, k);
      couple_one<15, 0>(Ush, acc, crow, k);
      couple_one<17, 0>(Ush, acc, crow, k);
      couple_one<19, 0>(Ush, acc, crow, k);
      couple_one<21, 0>(Ush, acc, crow, k);
    }
  } else {
    int q25 = (k < 25) ? k : 24;
    float acc[25];
#pragma unroll
    for (int j = 0; j < 25; ++j) acc[j] = 0.f;
    int i = beg + strm;
    int neC = 0;
    if (i < end) neC = nlist[i];
    while (i < end) {
      int i2 = i + 2;
      int neN = (i2 < end) ? nlist[i2] : 0;
      const unsigned short* rr = rad2 + (size_t)i * 352;
      const unsigned short* sr = S2v + (size_t)i * 168;
      const unsigned* fr = unc3 + (size_t)neC * 768;

      uint2 u3v = *reinterpret_cast<const uint2*>(rr + 224 + 4 * k);
      uint2 su3 = *reinterpret_cast<const uint2*>(sr + 64 + 4 * q25);
      unsigned fu3[13];
#pragma unroll
      for (int j = 0; j < 13; ++j) fu3[j] = fr[352 + j * 32 + k];

      float ra = lo2f(u3v.x), rb_ = hi2f(u3v.x), rc = lo2f(u3v.y), rd = hi2f(u3v.y);
#pragma unroll
      for (int i5 = 0; i5 < 5; ++i5) {
        float V5[5];
#pragma unroll
        for (int t = 0; t < 5; ++t) {
          int q = i5 * 5 + t;
          unsigned sx = (unsigned)__shfl((int)su3.x, q, 32);
          unsigned sy = (unsigned)__shfl((int)su3.y, q, 32);
          V5[t] = ra * lo2f(sx) + rb_ * hi2f(sx) + rc * lo2f(sy) + rd * hi2f(sy);
        }
#pragma unroll
        for (int j5 = 0; j5 < 5; ++j5) {
          float c = 0.f;
#pragma unroll
          for (int t = 0; t < 5; ++t) {
            int idx = t * 5 + j5;
            float F = (idx & 1) ? hi2f(fu3[idx >> 1]) : lo2f(fu3[idx >> 1]);
            c += V5[t] * F;
          }
          acc[i5 * 5 + j5] += c;
        }
      }
      i = i2; neC = neN;
    }
#pragma unroll
    for (int j = 0; j < 25; ++j) acc[j] += __shfl_xor(acc[j], 32);
    // couple: 16 lp==3 combos, 8 per half-wave (acc section shift 19)
    if (lane < 32) {
      couple_one<3, 19>(Ush, acc, crow, k);
      couple_one<6, 19>(Ush, acc, crow, k);
      couple_one<9, 19>(Ush, acc, crow, k);
      couple_one<12, 19>(Ush, acc, crow, k);
      couple_one<14, 19>(Ush, acc, crow, k);
      couple_one<16, 19>(Ush, acc, crow, k);
      couple_one<18, 19>(Ush, acc, crow, k);
      couple_one<20, 19>(Ush, acc, crow, k);
    } else {
      couple_one<22, 19>(Ush, acc, crow, k);
      couple_one<23, 19>(Ush, acc, crow, k);
      couple_one<24, 19>(Ush, acc, crow, k);
      couple_one<25, 19>(Ush, acc, crow, k);
      couple_one<26, 19>(Ush, acc, crow, k);
      couple_one<27, 19>(Ush, acc, crow, k);
      couple_one<28, 19>(Ush, acc, crow, k);
      couple_one<29, 19>(Ush, acc, crow, k);
    }
  }
}

// ---------------- k_out2: MFMA GEMM  out = feats + concat @ Wl ----------------
template <int l>
DEV void out_body(const float* __restrict__ ft, const float* __restrict__ wl,
                  const unsigned short* __restrict__ ccg, float* __restrict__ out,
                  int rt, int tid) {
  constexpr int NMM = 2 * l + 1;
  constexpr int K   = cK[l];
  constexpr int NKS = K / 32;
  constexpr int M   = N_ATOMS * NMM;
  constexpr int NET = (l <= 1) ? 4 : (l == 2 ? 2 : 1);
  int wv = tid >> 6, lane = tid & 63;
  int c0, et0;
  bool active = true;
  if constexpr (l == 0)      { c0 = wv * 32;       et0 = 0; }
  else if constexpr (l == 1) { c0 = wv * 32;       et0 = 0; active = (wv < 3); }
  else if constexpr (l == 2) { c0 = (wv & 1) * 32; et0 = (wv >> 1) * 2; }
  else                       { c0 = 0;             et0 = wv; }
  if (!active) return;
  int ln15 = lane & 15, lhi = lane >> 4;
  int r0 = rt * 64;
  short8 Bf[2][NKS];
#pragma unroll
  for (int ct = 0; ct < 2; ++ct)
#pragma unroll
    for (int ks = 0; ks < NKS; ++ks) {
      int col = c0 + ct * 16 + ln15;
      int kb  = ks * 32 + lhi * 8;
#pragma unroll
      for (int i = 0; i < 8; ++i)
        Bf[ct][ks][i] = f2bs(wl[(long)(kb + i) * K + col]);
    }
  long abase[NET];
#pragma unroll
  for (int et = 0; et < NET; ++et) {
    int R = r0 + (et0 + et) * 16 + ln15;
    if (R >= M) R = M - 1;
    int a = R / NMM, mm = R - a * NMM;
    abase[et] = (long)a * 960 + cCB[l] + (long)mm * K;
  }
  f32x4 acc[NET][2];
#pragma unroll
  for (int et = 0; et < NET; ++et)
#pragma unroll
    for (int ct = 0; ct < 2; ++ct) acc[et][ct] = (f32x4){0.f, 0.f, 0.f, 0.f};
#pragma unroll
  for (int et = 0; et < NET; ++et) {
#pragma unroll
    for (int ks = 0; ks < NKS; ++ks) {
      short8 Af = *reinterpret_cast<const short8*>(&ccg[abase[et] + ks * 32 + lhi * 8]);
      acc[et][0] = __builtin_amdgcn_mfma_f32_16x16x32_bf16(Af, Bf[0][ks], acc[et][0], 0, 0, 0);
      acc[et][1] = __builtin_amdgcn_mfma_f32_16x16x32_bf16(Af, Bf[1][ks], acc[et][1], 0, 0, 0);
    }
  }
#pragma unroll
  for (int et = 0; et < NET; ++et)
#pragma unroll
    for (int ct = 0; ct < 2; ++ct)
#pragma unroll
      for (int r = 0; r < 4; ++r) {
        int R = r0 + (et0 + et) * 16 + lhi * 4 + r;
        if (R < M) {
          int col = c0 + ct * 16 + ln15;
          long o = (long)R * K + col;
          out[cOUT[l] + o] = ft[o] + acc[et][ct][r];
        }
      }
}

__global__ __launch_bounds__(256) void k_out2(
    const float* __restrict__ f0, const float* __restrict__ f1,
    const float* __restrict__ f2, const float* __restrict__ f3,
    const float* __restrict__ wl0, const float* __restrict__ wl1,
    const float* __restrict__ wl2, const float* __restrict__ wl3,
    const unsigned short* __restrict__ ccg, float* __restrict__ out) {
  int b = blockIdx.x;
  int tid = threadIdx.x;
  if      (b < 40)  out_body<0>(f0, wl0, ccg, out, b,       tid);
  else if (b < 158) out_body<1>(f1, wl1, ccg, out, b - 40,  tid);
  else if (b < 354) out_body<2>(f2, wl2, ccg, out, b - 158, tid);
  else              out_body<3>(f3, wl3, ccg, out, b - 354, tid);
}

// ---------------- launch ----------------
extern "C" void kernel_launch(void* const* d_in, const int* in_sizes, int n_in,
                              void* d_out, int out_size, void* d_ws, size_t ws_size,
                              hipStream_t stream) {
  (void)n_in; (void)out_size; (void)ws_size;
  bool dictord = (in_sizes[1] == 40000);
  const float* rb[4]; const float* sph[4]; const float* ft[4];
  const float *w1[4], *w2[4], *wl[4];
  for (int l = 0; l < 4; ++l) {
    if (dictord) {
      rb[l]  = (const float*)d_in[3 * l + 0];
      sph[l] = (const float*)d_in[3 * l + 1];
      ft[l]  = (const float*)d_in[3 * l + 2];
      w1[l]  = (const float*)d_in[17 + 3 * l];
      w2[l]  = (const float*)d_in[18 + 3 * l];
      wl[l]  = (const float*)d_in[19 + 3 * l];
    } else {
      rb[l]  = (const float*)d_in[l];
      sph[l] = (const float*)d_in[4 + l];
      ft[l]  = (const float*)d_in[8 + l];
      w1[l]  = (const float*)d_in[17 + l];
      w2[l]  = (const float*)d_in[21 + l];
      wl[l]  = (const float*)d_in[25 + l];
    }
  }
  const int* centers   = (const int*)d_in[12];
  const int* neighbors = (const int*)d_in[13];
  const float* u0 = (const float*)d_in[14];
  const float* u2 = (const float*)d_in[15];
  const float* u4 = (const float*)d_in[16];

  float* ws = (float*)d_ws;
  unsigned short* rad2 = (unsigned short*)(ws + RAD2_OFF);
  unsigned short* S2v  = (unsigned short*)(ws + S2_OFF);
  unsigned*       unc3 = (unsigned*)(ws + UNC3_OFF);
  unsigned short* ccg  = (unsigned short*)(ws + CCG_OFF);
  int* cnt   = (int*)(ws + CNT_OFF);
  int* start = (int*)(ws + START_OFF);
  int* fill  = (int*)(ws + FILL_OFF);
  int* inv   = (int*)(ws + INV_OFF);
  int* nlist = (int*)(ws + NLIST_OFF);

  hipMemsetAsync(cnt, 0, N_ATOMS * sizeof(int), stream);
  k_count<<<157, 256, 0, stream>>>(centers, cnt);
  k_scan<<<1, 256, 0, stream>>>(cnt, start, fill);
  k_fill<<<157, 256, 0, stream>>>(centers, neighbors, fill, inv, nlist);
  k_mid<<<7813, 256, 0, stream>>>(rb[0], rb[1], rb[2], rb[3],
                                  sph[0], sph[1], sph[2], sph[3],
                                  ft[0], ft[1], ft[2], ft[3],
                                  w1[0], w1[1], w1[2], w1[3],
                                  w2[0], w2[1], w2[2], w2[3],
                                  u0, u2, u4, inv, rad2, S2v, unc3);
  k_edge8<<<1250, 256, 0, stream>>>(start, nlist, u0, u2, u4,
                                    rad2, S2v, unc3, ccg);
  k_out2<<<628, 256, 0, stream>>>(ft[0], ft[1], ft[2], ft[3],
                                  wl[0], wl[1], wl[2], wl[3], ccg, (float*)d_out);
}